// Round 1
// baseline (569.089 us; speedup 1.0000x reference)
//
#include <hip/hip_runtime.h>
#include <math.h>

#define Bdim 4
#define Sdim 4096
#define Gdim 4
#define Ddim 256
#define Ndim 128
#define NTOK (Bdim*Sdim*Gdim)      // 65536 tokens
#define CHUNKS 64
#define CLEN (Sdim/CHUNKS)         // 64 steps per chunk
#define NCHAN (Bdim*Gdim*Ndim)     // 2048 scan channels

// ---------------------------------------------------------------------------
// Kernel 1: dt projection. One wave (64 lanes) per token.
// logit_o = sum_k x_cat[k]*dt_w[o][k] + dt_b[o];  dt = clip(exp(logit),1e-4,2)
// ---------------------------------------------------------------------------
__global__ __launch_bounds__(256) void dt_kernel(
    const float* __restrict__ xr, const float* __restrict__ xi,
    const float* __restrict__ dtw, const float* __restrict__ dtb,
    float* __restrict__ dtm, float* __restrict__ dtp)
{
    const int gtid = blockIdx.x * 256 + threadIdx.x;
    const int tok  = gtid >> 6;
    const int lane = gtid & 63;
    if (tok >= NTOK) return;

    const float4 a  = *(const float4*)(xr  + (size_t)tok * Ddim + lane * 4);
    const float4 b4 = *(const float4*)(xi  + (size_t)tok * Ddim + lane * 4);
    const float4 c0 = *(const float4*)(dtw +   0 + lane * 4);   // dt_w[0][0:256]
    const float4 d0 = *(const float4*)(dtw + 256 + lane * 4);   // dt_w[0][256:512]
    const float4 c1 = *(const float4*)(dtw + 512 + lane * 4);   // dt_w[1][0:256]
    const float4 d1 = *(const float4*)(dtw + 768 + lane * 4);   // dt_w[1][256:512]

    float l0 = a.x*c0.x + a.y*c0.y + a.z*c0.z + a.w*c0.w
             + b4.x*d0.x + b4.y*d0.y + b4.z*d0.z + b4.w*d0.w;
    float l1 = a.x*c1.x + a.y*c1.y + a.z*c1.z + a.w*c1.w
             + b4.x*d1.x + b4.y*d1.y + b4.z*d1.z + b4.w*d1.w;

    #pragma unroll
    for (int off = 32; off; off >>= 1) {
        l0 += __shfl_down(l0, off);
        l1 += __shfl_down(l1, off);
    }
    if (lane == 0) {
        float m = expf(l0 + dtb[0]); m = fminf(fmaxf(m, 1e-4f), 2.0f);
        float p = expf(l1 + dtb[1]); p = fminf(fmaxf(p, 1e-4f), 2.0f);
        dtm[tok] = m;
        dtp[tok] = p;
    }
}

// ---------------------------------------------------------------------------
// Kernel 2: f64 cumsum of dt_mag / dt_phase along S per (b,g) sequence.
// One block per (b,g). Hillis-Steele over 256-element segments + carry.
// ---------------------------------------------------------------------------
__global__ __launch_bounds__(256) void cumsum_kernel(
    const float* __restrict__ dtm, const float* __restrict__ dtp,
    double* __restrict__ cumM, double* __restrict__ cumP)
{
    const int bg = blockIdx.x;
    const int b = bg >> 2, g = bg & 3;
    __shared__ double sm[256], sp[256];
    const int tid = threadIdx.x;
    double carryM = 0.0, carryP = 0.0;

    for (int seg = 0; seg < Sdim / 256; ++seg) {
        const int s = seg * 256 + tid;
        const size_t tok = ((size_t)(b * Sdim + s)) * Gdim + g;
        sm[tid] = (double)dtm[tok];
        sp[tid] = (double)dtp[tok];
        __syncthreads();
        for (int off = 1; off < 256; off <<= 1) {
            double am = (tid >= off) ? sm[tid - off] : 0.0;
            double ap = (tid >= off) ? sp[tid - off] : 0.0;
            __syncthreads();
            sm[tid] += am;
            sp[tid] += ap;
            __syncthreads();
        }
        cumM[tok] = carryM + sm[tid];
        cumP[tok] = carryP + sp[tid];
        carryM += sm[255];
        carryP += sp[255];
        __syncthreads();
    }
}

// ---------------------------------------------------------------------------
// Kernel 3: Bx GEMM (fp32). M=NTOK, Nout=256 (o<128: Bxr[o], o>=128: Bxi),
// K=512 (k<256: x_real, k>=256: x_imag).
//   Bxr[n] = sum_d xr*Bwr[n,d] - xi*Bwi[n,d]
//   Bxi[n] = sum_d xr*Bwi[n,d] + xi*Bwr[n,d]
// 64x64 tile, BK=16, 256 threads, 4x4 per thread.
// ---------------------------------------------------------------------------
__global__ __launch_bounds__(256) void gemm_bx_kernel(
    const float* __restrict__ xr, const float* __restrict__ xi,
    const float* __restrict__ Bwr, const float* __restrict__ Bwi,
    float* __restrict__ bx)
{
    __shared__ float As[16][64];
    __shared__ float Ws[16][64];
    const int tid = threadIdx.x;
    const int bm = blockIdx.x;
    const int o0 = blockIdx.y * 64;
    const bool isI = (o0 >= 128);
    const int n0 = isI ? (o0 - 128) : o0;
    const int lr = tid >> 2;            // 0..63
    const int lc = (tid & 3) << 2;      // 0,4,8,12
    const int ty = tid >> 4, tx = tid & 15;
    const size_t m0 = (size_t)bm * 64;
    float acc[4][4] = {};

    for (int k0 = 0; k0 < 512; k0 += 16) {
        const bool hi = (k0 >= 256);
        const int kb = (k0 & 255) + lc;
        const float* xsrc = hi ? xi : xr;
        const float4 av = *(const float4*)(xsrc + (m0 + lr) * Ddim + kb);
        const float* wsrc = (isI != hi) ? Bwi : Bwr;
        const float sgn = (!isI && hi) ? -1.0f : 1.0f;
        const float4 wv = *(const float4*)(wsrc + (size_t)(n0 + lr) * Ddim + kb);

        As[lc + 0][lr] = av.x; As[lc + 1][lr] = av.y;
        As[lc + 2][lr] = av.z; As[lc + 3][lr] = av.w;
        Ws[lc + 0][lr] = sgn * wv.x; Ws[lc + 1][lr] = sgn * wv.y;
        Ws[lc + 2][lr] = sgn * wv.z; Ws[lc + 3][lr] = sgn * wv.w;
        __syncthreads();

        #pragma unroll
        for (int kk = 0; kk < 16; ++kk) {
            const float4 a = *(const float4*)&As[kk][ty << 2];
            const float4 w = *(const float4*)&Ws[kk][tx << 2];
            acc[0][0] += a.x*w.x; acc[0][1] += a.x*w.y; acc[0][2] += a.x*w.z; acc[0][3] += a.x*w.w;
            acc[1][0] += a.y*w.x; acc[1][1] += a.y*w.y; acc[1][2] += a.y*w.z; acc[1][3] += a.y*w.w;
            acc[2][0] += a.z*w.x; acc[2][1] += a.z*w.y; acc[2][2] += a.z*w.z; acc[2][3] += a.z*w.w;
            acc[3][0] += a.w*w.x; acc[3][1] += a.w*w.y; acc[3][2] += a.w*w.z; acc[3][3] += a.w*w.w;
        }
        __syncthreads();
    }
    #pragma unroll
    for (int i = 0; i < 4; ++i) {
        #pragma unroll
        for (int j = 0; j < 4; ++j) {
            bx[(m0 + (ty * 4 + i)) * 256 + o0 + tx * 4 + j] = acc[i][j];
        }
    }
}

// ---------------------------------------------------------------------------
// Kernels 4/6: chunked scan. Block = (chunk c, (b,g)); 128 threads = one per n.
// Replicates: cl = cumsum(log_A); cumA = exp(cl.r)*(cos,sin)(cl.i);
//             u = Bx*dt_mag/(cumA + 1e-12); S = cumsum(u); h = cumA*S; clip.
// PASS 0: chunk totals of u.  PASS 1: with chunk prefix, emit clipped h
// (in-place over bx).
// ---------------------------------------------------------------------------
template<int PASS>
__global__ __launch_bounds__(128) void scan_kernel(
    const float* __restrict__ bx, float* __restrict__ hout,
    const float* __restrict__ dtm,
    const double* __restrict__ cumM, const double* __restrict__ cumP,
    const float* __restrict__ logAmag, const float* __restrict__ Aphase,
    float2* __restrict__ Tc, const float2* __restrict__ Pc)
{
    const int c = blockIdx.x;
    const int bg = blockIdx.y;
    const int b = bg >> 2, g = bg & 3;
    const int n = threadIdx.x;
    const double nlAd = (double)(-log1pf(expf(logAmag[g * Ndim + n])));
    const double aphd = (double)(Aphase[g * Ndim + n]);

    float Sr = 0.0f, Si = 0.0f;
    if (PASS == 1) {
        const float2 p = Pc[(size_t)c * NCHAN + bg * Ndim + n];
        Sr = p.x; Si = p.y;
    }
    const int s0 = c * CLEN;
    for (int j = 0; j < CLEN; ++j) {
        const int s = s0 + j;
        const size_t tok = ((size_t)(b * Sdim + s)) * Gdim + g;
        const float clr = (float)(nlAd * cumM[tok]);
        const float cli = (float)(aphd * cumP[tok]);
        const float dt = dtm[tok];
        const float e = expf(clr);                 // underflows to 0 like ref
        float sn, cs;
        sincosf(cli, &sn, &cs);
        const float car = e * cs, cai = e * sn;    // cumA
        const float dr = car + 1e-12f, di = cai;   // cumA + 1e-12 (real eps)
        const float inv = 1.0f / (dr * dr + di * di);
        const float bxr = bx[tok * 256 + n] * dt;
        const float bxi = bx[tok * 256 + 128 + n] * dt;
        Sr += (bxr * dr + bxi * di) * inv;
        Si += (bxi * dr - bxr * di) * inv;
        if (PASS == 1) {
            const float hr = car * Sr - cai * Si;
            const float hi2 = car * Si + cai * Sr;
            const float nrm = sqrtf(hr * hr + hi2 * hi2 + 1e-8f);
            const float scl = fminf(nrm, 100.0f) / nrm;
            hout[tok * 256 + n]       = hr * scl;
            hout[tok * 256 + 128 + n] = hi2 * scl;
        }
    }
    if (PASS == 0) Tc[(size_t)c * NCHAN + bg * Ndim + n] = make_float2(Sr, Si);
}

// ---------------------------------------------------------------------------
// Kernel 5: exclusive prefix over chunk totals. One thread per channel.
// ---------------------------------------------------------------------------
__global__ __launch_bounds__(256) void chunk_prefix_kernel(
    const float2* __restrict__ Tc, float2* __restrict__ Pc)
{
    const int ch = blockIdx.x * 256 + threadIdx.x;
    if (ch >= NCHAN) return;
    float Sr = 0.0f, Si = 0.0f;
    for (int c = 0; c < CHUNKS; ++c) {
        const float2 t = Tc[(size_t)c * NCHAN + ch];
        Pc[(size_t)c * NCHAN + ch] = make_float2(Sr, Si);
        Sr += t.x; Si += t.y;
    }
}

// ---------------------------------------------------------------------------
// Kernel 7: y GEMM (fp32). M=NTOK, Nout=512 (o<256: yr[d=o], o>=256: yi),
// K=256 (kk<128: h_r, kk>=128: h_i).
//   yr[d] = sum_n hr*Cwr[d,n] - hi*Cwi[d,n]
//   yi[d] = sum_n hr*Cwi[d,n] + hi*Cwr[d,n]
// ---------------------------------------------------------------------------
__global__ __launch_bounds__(256) void gemm_y_kernel(
    const float* __restrict__ h,
    const float* __restrict__ Cwr, const float* __restrict__ Cwi,
    float* __restrict__ out)
{
    __shared__ float As[16][64];
    __shared__ float Ws[16][64];
    const int tid = threadIdx.x;
    const int bm = blockIdx.x;
    const int o0 = blockIdx.y * 64;
    const bool isYi = (o0 >= 256);
    const int d0 = isYi ? (o0 - 256) : o0;
    const int lr = tid >> 2;
    const int lc = (tid & 3) << 2;
    const int ty = tid >> 4, tx = tid & 15;
    const size_t m0 = (size_t)bm * 64;
    float acc[4][4] = {};

    for (int k0 = 0; k0 < 256; k0 += 16) {
        const bool hi = (k0 >= 128);
        const int kb = (k0 & 127) + lc;
        const float4 av = *(const float4*)(h + (m0 + lr) * 256 + k0 + lc);
        const float* wsrc = (isYi != hi) ? Cwi : Cwr;
        const float sgn = (!isYi && hi) ? -1.0f : 1.0f;
        const float4 wv = *(const float4*)(wsrc + (size_t)(d0 + lr) * Ndim + kb);

        As[lc + 0][lr] = av.x; As[lc + 1][lr] = av.y;
        As[lc + 2][lr] = av.z; As[lc + 3][lr] = av.w;
        Ws[lc + 0][lr] = sgn * wv.x; Ws[lc + 1][lr] = sgn * wv.y;
        Ws[lc + 2][lr] = sgn * wv.z; Ws[lc + 3][lr] = sgn * wv.w;
        __syncthreads();

        #pragma unroll
        for (int kk = 0; kk < 16; ++kk) {
            const float4 a = *(const float4*)&As[kk][ty << 2];
            const float4 w = *(const float4*)&Ws[kk][tx << 2];
            acc[0][0] += a.x*w.x; acc[0][1] += a.x*w.y; acc[0][2] += a.x*w.z; acc[0][3] += a.x*w.w;
            acc[1][0] += a.y*w.x; acc[1][1] += a.y*w.y; acc[1][2] += a.y*w.z; acc[1][3] += a.y*w.w;
            acc[2][0] += a.z*w.x; acc[2][1] += a.z*w.y; acc[2][2] += a.z*w.z; acc[2][3] += a.z*w.w;
            acc[3][0] += a.w*w.x; acc[3][1] += a.w*w.y; acc[3][2] += a.w*w.z; acc[3][3] += a.w*w.w;
        }
        __syncthreads();
    }
    #pragma unroll
    for (int i = 0; i < 4; ++i) {
        #pragma unroll
        for (int j = 0; j < 4; ++j) {
            out[(m0 + (ty * 4 + i)) * 512 + o0 + tx * 4 + j] = acc[i][j];
        }
    }
}

// ---------------------------------------------------------------------------
extern "C" void kernel_launch(void* const* d_in, const int* in_sizes, int n_in,
                              void* d_out, int out_size, void* d_ws, size_t ws_size,
                              hipStream_t stream)
{
    const float* xr      = (const float*)d_in[0];
    const float* xi      = (const float*)d_in[1];
    const float* logAmag = (const float*)d_in[2];
    const float* Aphase  = (const float*)d_in[3];
    const float* Bwr     = (const float*)d_in[4];
    const float* Bwi     = (const float*)d_in[5];
    const float* Cwr     = (const float*)d_in[6];
    const float* Cwi     = (const float*)d_in[7];
    const float* dtw     = (const float*)d_in[8];
    const float* dtb     = (const float*)d_in[9];
    float* out = (float*)d_out;

    char* ws = (char*)d_ws;
    size_t off = 0;
    float* bx = (float*)(ws + off);   off += (size_t)NTOK * 256 * sizeof(float); // 64 MiB (Bx, then h in-place)
    float* dtm = (float*)(ws + off);  off += (size_t)NTOK * sizeof(float);
    float* dtp = (float*)(ws + off);  off += (size_t)NTOK * sizeof(float);
    double* cumM = (double*)(ws + off); off += (size_t)NTOK * sizeof(double);
    double* cumP = (double*)(ws + off); off += (size_t)NTOK * sizeof(double);
    float2* Tc = (float2*)(ws + off); off += (size_t)CHUNKS * NCHAN * sizeof(float2);
    float2* Pc = (float2*)(ws + off); off += (size_t)CHUNKS * NCHAN * sizeof(float2);

    dt_kernel<<<NTOK / 4, 256, 0, stream>>>(xr, xi, dtw, dtb, dtm, dtp);
    cumsum_kernel<<<Bdim * Gdim, 256, 0, stream>>>(dtm, dtp, cumM, cumP);
    gemm_bx_kernel<<<dim3(NTOK / 64, 4), 256, 0, stream>>>(xr, xi, Bwr, Bwi, bx);
    scan_kernel<0><<<dim3(CHUNKS, Bdim * Gdim), 128, 0, stream>>>(
        bx, bx, dtm, cumM, cumP, logAmag, Aphase, Tc, Pc);
    chunk_prefix_kernel<<<(NCHAN + 255) / 256, 256, 0, stream>>>(Tc, Pc);
    scan_kernel<1><<<dim3(CHUNKS, Bdim * Gdim), 128, 0, stream>>>(
        bx, bx, dtm, cumM, cumP, logAmag, Aphase, Tc, Pc);
    gemm_y_kernel<<<dim3(NTOK / 64, 8), 256, 0, stream>>>(bx, Cwr, Cwi, out);
}

// Round 2
// 305.612 us; speedup vs baseline: 1.8621x; 1.8621x over previous
//
#include <hip/hip_runtime.h>
#include <math.h>

#define Bdim 4
#define Sdim 4096
#define Gdim 4
#define Ddim 256
#define Ndim 128
#define NTOK (Bdim*Sdim*Gdim)      // 65536 tokens
#define CHUNKS 64
#define CLEN (Sdim/CHUNKS)         // 64 steps per chunk
#define NCHAN (Bdim*Gdim*Ndim)     // 2048 scan channels

typedef unsigned short u16;
typedef unsigned int   u32;
typedef __attribute__((ext_vector_type(8))) short bf16x8;
typedef __attribute__((ext_vector_type(4))) float f32x4;

#define GLOBAL_AS __attribute__((address_space(1)))
#define LDS_AS    __attribute__((address_space(3)))

__device__ __forceinline__ void gl_lds16(const void* g, void* l) {
    __builtin_amdgcn_global_load_lds((const GLOBAL_AS u32*)g, (LDS_AS u32*)l, 16, 0, 0);
}

__device__ __forceinline__ u16 f2bf(float f) {          // RNE fp32 -> bf16
    u32 u = __float_as_uint(f);
    return (u16)((u + 0x7fffu + ((u >> 16) & 1u)) >> 16);
}
__device__ __forceinline__ float bf2f(u16 h) { return __uint_as_float(((u32)h) << 16); }

// ---------------------------------------------------------------------------
// Weight prep: build bf16 hi/lo combined matrices.
// Wbx [256 n][512 k]:  n<128 (real out): k<256 Bwr[n,k], k>=256 -Bwi[n,k-256]
//                      n>=128 (imag)   : k<256 Bwi[n',k], k>=256  Bwr[n',k-256]
// Wy  [512 d][256 k]:  d<256 (yr): k<128 Cwr[d,k], k>=128 -Cwi[d,k-128]
//                      d>=256(yi): k<128 Cwi[d',k], k>=128  Cwr[d',k-128]
// ---------------------------------------------------------------------------
__global__ __launch_bounds__(256) void prep_weights(
    const float* __restrict__ Bwr, const float* __restrict__ Bwi,
    const float* __restrict__ Cwr, const float* __restrict__ Cwi,
    u16* __restrict__ WbxH, u16* __restrict__ WbxL,
    u16* __restrict__ WyH,  u16* __restrict__ WyL)
{
    const int idx = blockIdx.x * 256 + threadIdx.x;   // 0..131071
    {
        const int n = idx >> 9, k = idx & 511;
        float v;
        if (n < 128) v = (k < 256) ? Bwr[n * 256 + k] : -Bwi[n * 256 + (k - 256)];
        else         v = (k < 256) ? Bwi[(n - 128) * 256 + k] : Bwr[(n - 128) * 256 + (k - 256)];
        const u16 h = f2bf(v);
        WbxH[idx] = h; WbxL[idx] = f2bf(v - bf2f(h));
    }
    {
        const int d = idx >> 8, k = idx & 255;
        float v;
        if (d < 256) v = (k < 128) ? Cwr[d * 128 + k] : -Cwi[d * 128 + (k - 128)];
        else         v = (k < 128) ? Cwi[(d - 256) * 128 + k] : Cwr[(d - 256) * 128 + (k - 128)];
        const u16 h = f2bf(v);
        WyH[idx] = h; WyL[idx] = f2bf(v - bf2f(h));
    }
}

// ---------------------------------------------------------------------------
// dt projection + xcat bf16 hi/lo emission. One wave per token.
// xcat[tok][512]: k<256 = xr[d], k>=256 = xi[d]  (hi and lo arrays, in d_out)
// ---------------------------------------------------------------------------
__global__ __launch_bounds__(256) void dt_kernel(
    const float* __restrict__ xr, const float* __restrict__ xi,
    const float* __restrict__ dtw, const float* __restrict__ dtb,
    float* __restrict__ dtm, float* __restrict__ dtp,
    u16* __restrict__ xch, u16* __restrict__ xcl)
{
    const int gtid = blockIdx.x * 256 + threadIdx.x;
    const int tok  = gtid >> 6;
    const int lane = gtid & 63;
    if (tok >= NTOK) return;

    const float4 a  = *(const float4*)(xr  + (size_t)tok * Ddim + lane * 4);
    const float4 b4 = *(const float4*)(xi  + (size_t)tok * Ddim + lane * 4);
    const float4 c0 = *(const float4*)(dtw +   0 + lane * 4);
    const float4 d0 = *(const float4*)(dtw + 256 + lane * 4);
    const float4 c1 = *(const float4*)(dtw + 512 + lane * 4);
    const float4 d1 = *(const float4*)(dtw + 768 + lane * 4);

    // emit xcat bf16 hi/lo (packed 2x per u32)
    {
        const u16 h0 = f2bf(a.x), h1 = f2bf(a.y), h2 = f2bf(a.z), h3 = f2bf(a.w);
        const u16 l0 = f2bf(a.x - bf2f(h0)), l1 = f2bf(a.y - bf2f(h1));
        const u16 l2 = f2bf(a.z - bf2f(h2)), l3 = f2bf(a.w - bf2f(h3));
        *(uint2*)(xch + (size_t)tok * 512 + lane * 4) = make_uint2((u32)h0 | ((u32)h1 << 16), (u32)h2 | ((u32)h3 << 16));
        *(uint2*)(xcl + (size_t)tok * 512 + lane * 4) = make_uint2((u32)l0 | ((u32)l1 << 16), (u32)l2 | ((u32)l3 << 16));
    }
    {
        const u16 h0 = f2bf(b4.x), h1 = f2bf(b4.y), h2 = f2bf(b4.z), h3 = f2bf(b4.w);
        const u16 l0 = f2bf(b4.x - bf2f(h0)), l1 = f2bf(b4.y - bf2f(h1));
        const u16 l2 = f2bf(b4.z - bf2f(h2)), l3 = f2bf(b4.w - bf2f(h3));
        *(uint2*)(xch + (size_t)tok * 512 + 256 + lane * 4) = make_uint2((u32)h0 | ((u32)h1 << 16), (u32)h2 | ((u32)h3 << 16));
        *(uint2*)(xcl + (size_t)tok * 512 + 256 + lane * 4) = make_uint2((u32)l0 | ((u32)l1 << 16), (u32)l2 | ((u32)l3 << 16));
    }

    float r0 = a.x*c0.x + a.y*c0.y + a.z*c0.z + a.w*c0.w
             + b4.x*d0.x + b4.y*d0.y + b4.z*d0.z + b4.w*d0.w;
    float r1 = a.x*c1.x + a.y*c1.y + a.z*c1.z + a.w*c1.w
             + b4.x*d1.x + b4.y*d1.y + b4.z*d1.z + b4.w*d1.w;
    #pragma unroll
    for (int off = 32; off; off >>= 1) {
        r0 += __shfl_down(r0, off);
        r1 += __shfl_down(r1, off);
    }
    if (lane == 0) {
        float m = expf(r0 + dtb[0]); m = fminf(fmaxf(m, 1e-4f), 2.0f);
        float p = expf(r1 + dtb[1]); p = fminf(fmaxf(p, 1e-4f), 2.0f);
        dtm[tok] = m;
        dtp[tok] = p;
    }
}

// ---------------------------------------------------------------------------
// f64 cumsum of dt_mag / dt_phase along S per (b,g) sequence.
// ---------------------------------------------------------------------------
__global__ __launch_bounds__(256) void cumsum_kernel(
    const float* __restrict__ dtm, const float* __restrict__ dtp,
    double* __restrict__ cumM, double* __restrict__ cumP)
{
    const int bg = blockIdx.x;
    const int b = bg >> 2, g = bg & 3;
    __shared__ double sm[256], sp[256];
    const int tid = threadIdx.x;
    double carryM = 0.0, carryP = 0.0;

    for (int seg = 0; seg < Sdim / 256; ++seg) {
        const int s = seg * 256 + tid;
        const size_t tok = ((size_t)(b * Sdim + s)) * Gdim + g;
        sm[tid] = (double)dtm[tok];
        sp[tid] = (double)dtp[tok];
        __syncthreads();
        for (int off = 1; off < 256; off <<= 1) {
            double am = (tid >= off) ? sm[tid - off] : 0.0;
            double ap = (tid >= off) ? sp[tid - off] : 0.0;
            __syncthreads();
            sm[tid] += am;
            sp[tid] += ap;
            __syncthreads();
        }
        cumM[tok] = carryM + sm[tid];
        cumP[tok] = carryP + sp[tid];
        carryM += sm[255];
        carryP += sp[255];
        __syncthreads();
    }
}

// ---------------------------------------------------------------------------
// GEMM 1 (MFMA bf16x3): bx[M][256] = xcat[M][512] . Wbx[256][512]^T
// A hi/lo separate bf16 arrays. Tile 128x128, BK=32, 4 waves (2x2 of 64x64).
// ---------------------------------------------------------------------------
__global__ __launch_bounds__(256) void gemm_bx_mfma(
    const u16* __restrict__ Ah, const u16* __restrict__ Al,
    const u16* __restrict__ Wh, const u16* __restrict__ Wl,
    float* __restrict__ Cout)
{
    __shared__ u16 sAh[128 * 32], sAl[128 * 32], sWh[128 * 32], sWl[128 * 32];
    const int tid = threadIdx.x, wave = tid >> 6, lane = tid & 63;
    const size_t m0 = (size_t)blockIdx.y * 128;
    const int n0 = blockIdx.x * 128;
    const int wm = (wave >> 1) * 64, wn = (wave & 1) * 64;
    f32x4 acc[4][4] = {};

    const int srow = lane >> 2;      // 0..15 (row within 16-row issue group)
    const int pslot = lane & 3;      // physical 16B slot within 64B row

    #pragma unroll 1
    for (int k0 = 0; k0 < 512; k0 += 32) {
        #pragma unroll
        for (int i = 0; i < 2; ++i) {
            const int row = wave * 32 + i * 16 + srow;
            const int lslot = pslot ^ ((row >> 1) & 3);       // inverse-swizzled source
            const int ldsoff = row * 32 + pslot * 8;          // linear dest (u16 units)
            const size_t gA = (m0 + row) * 512 + k0 + lslot * 8;
            const size_t gW = ((size_t)(n0 + row)) * 512 + k0 + lslot * 8;
            gl_lds16(Ah + gA, sAh + ldsoff);
            gl_lds16(Al + gA, sAl + ldsoff);
            gl_lds16(Wh + gW, sWh + ldsoff);
            gl_lds16(Wl + gW, sWl + ldsoff);
        }
        __syncthreads();

        const int fr = lane & 15;
        const int fs = lane >> 4;    // logical k-chunk (8 bf16)
        bf16x8 ah[4], al[4], wh[4], wl[4];
        #pragma unroll
        for (int f = 0; f < 4; ++f) {
            const int ra = wm + f * 16 + fr;
            const int oa = ra * 32 + (fs ^ ((ra >> 1) & 3)) * 8;
            ah[f] = *(const bf16x8*)&sAh[oa];
            al[f] = *(const bf16x8*)&sAl[oa];
            const int rw = wn + f * 16 + fr;
            const int ow = rw * 32 + (fs ^ ((rw >> 1) & 3)) * 8;
            wh[f] = *(const bf16x8*)&sWh[ow];
            wl[f] = *(const bf16x8*)&sWl[ow];
        }
        #pragma unroll
        for (int fm = 0; fm < 4; ++fm)
            #pragma unroll
            for (int fn = 0; fn < 4; ++fn) {
                acc[fm][fn] = __builtin_amdgcn_mfma_f32_16x16x32_bf16(ah[fm], wh[fn], acc[fm][fn], 0, 0, 0);
                acc[fm][fn] = __builtin_amdgcn_mfma_f32_16x16x32_bf16(ah[fm], wl[fn], acc[fm][fn], 0, 0, 0);
                acc[fm][fn] = __builtin_amdgcn_mfma_f32_16x16x32_bf16(al[fm], wh[fn], acc[fm][fn], 0, 0, 0);
            }
        __syncthreads();
    }

    const int crow = (lane >> 4) * 4, ccol = lane & 15;
    #pragma unroll
    for (int fm = 0; fm < 4; ++fm)
        #pragma unroll
        for (int fn = 0; fn < 4; ++fn)
            #pragma unroll
            for (int j = 0; j < 4; ++j)
                Cout[(m0 + wm + fm * 16 + crow + j) * 256 + n0 + wn + fn * 16 + ccol] = acc[fm][fn][j];
}

// ---------------------------------------------------------------------------
// Chunked scan. PASS 0: chunk totals. PASS 1: emit h as packed bf16 hi|lo<<16,
// IN PLACE over bx (read fp32 slot, write packed u32 same slot).
// ---------------------------------------------------------------------------
template<int PASS>
__global__ __launch_bounds__(128) void scan_kernel(
    float* __restrict__ bxbuf,
    const float* __restrict__ dtm,
    const double* __restrict__ cumM, const double* __restrict__ cumP,
    const float* __restrict__ logAmag, const float* __restrict__ Aphase,
    float2* __restrict__ Tc, const float2* __restrict__ Pc)
{
    const int c = blockIdx.x;
    const int bg = blockIdx.y;
    const int b = bg >> 2, g = bg & 3;
    const int n = threadIdx.x;
    const double nlAd = (double)(-log1pf(expf(logAmag[g * Ndim + n])));
    const double aphd = (double)(Aphase[g * Ndim + n]);

    float Sr = 0.0f, Si = 0.0f;
    if (PASS == 1) {
        const float2 p = Pc[(size_t)c * NCHAN + bg * Ndim + n];
        Sr = p.x; Si = p.y;
    }
    const int s0 = c * CLEN;
    for (int j = 0; j < CLEN; ++j) {
        const int s = s0 + j;
        const size_t tok = ((size_t)(b * Sdim + s)) * Gdim + g;
        const float clr = (float)(nlAd * cumM[tok]);
        const float cli = (float)(aphd * cumP[tok]);
        const float dt = dtm[tok];
        const float e = expf(clr);
        float sn, cs;
        sincosf(cli, &sn, &cs);
        const float car = e * cs, cai = e * sn;
        const float dr = car + 1e-12f, di = cai;
        const float inv = 1.0f / (dr * dr + di * di);
        const float bxr = bxbuf[tok * 256 + n] * dt;
        const float bxi = bxbuf[tok * 256 + 128 + n] * dt;
        Sr += (bxr * dr + bxi * di) * inv;
        Si += (bxi * dr - bxr * di) * inv;
        if (PASS == 1) {
            const float hr  = car * Sr - cai * Si;
            const float hi2 = car * Si + cai * Sr;
            const float nrm = sqrtf(hr * hr + hi2 * hi2 + 1e-8f);
            const float scl = fminf(nrm, 100.0f) / nrm;
            const float hrc = hr * scl, hic = hi2 * scl;
            const u16 rh = f2bf(hrc); const u16 rl = f2bf(hrc - bf2f(rh));
            const u16 ih = f2bf(hic); const u16 il = f2bf(hic - bf2f(ih));
            ((u32*)bxbuf)[tok * 256 + n]       = (u32)rh | ((u32)rl << 16);
            ((u32*)bxbuf)[tok * 256 + 128 + n] = (u32)ih | ((u32)il << 16);
        }
    }
    if (PASS == 0) Tc[(size_t)c * NCHAN + bg * Ndim + n] = make_float2(Sr, Si);
}

// ---------------------------------------------------------------------------
// Exclusive prefix over chunk totals.
// ---------------------------------------------------------------------------
__global__ __launch_bounds__(256) void chunk_prefix_kernel(
    const float2* __restrict__ Tc, float2* __restrict__ Pc)
{
    const int ch = blockIdx.x * 256 + threadIdx.x;
    if (ch >= NCHAN) return;
    float Sr = 0.0f, Si = 0.0f;
    for (int c = 0; c < CHUNKS; ++c) {
        const float2 t = Tc[(size_t)c * NCHAN + ch];
        Pc[(size_t)c * NCHAN + ch] = make_float2(Sr, Si);
        Sr += t.x; Si += t.y;
    }
}

// ---------------------------------------------------------------------------
// GEMM 2 (MFMA bf16x3): out[M][512] = h[M][256] . Wy[512][256]^T
// A is packed u32 (bf16 hi | lo<<16). Tile 128x128, BK=32.
// ---------------------------------------------------------------------------
__global__ __launch_bounds__(256) void gemm_y_mfma(
    const u32* __restrict__ Hpk,
    const u16* __restrict__ Wh, const u16* __restrict__ Wl,
    float* __restrict__ Cout)
{
    __shared__ u32 sA[128 * 32];                    // 16 KB packed (rows 128 B)
    __shared__ u16 sWh[128 * 32], sWl[128 * 32];    // 8 KB each (rows 64 B)
    const int tid = threadIdx.x, wave = tid >> 6, lane = tid & 63;
    const size_t m0 = (size_t)blockIdx.y * 128;
    const int n0 = blockIdx.x * 128;
    const int wm = (wave >> 1) * 64, wn = (wave & 1) * 64;
    f32x4 acc[4][4] = {};

    #pragma unroll 1
    for (int k0 = 0; k0 < 256; k0 += 32) {
        // stage A: 128 rows x 32 u32 (128 B rows, 8 slots of 16 B)
        #pragma unroll
        for (int i = 0; i < 4; ++i) {
            const int row = wave * 32 + i * 8 + (lane >> 3);
            const int p = lane & 7;
            const int ls = p ^ (row & 7);
            gl_lds16(Hpk + (m0 + row) * 256 + k0 + ls * 4, sA + row * 32 + p * 4);
        }
        // stage W hi/lo: 128 rows x 32 u16 (64 B rows, 4 slots)
        #pragma unroll
        for (int i = 0; i < 2; ++i) {
            const int row = wave * 32 + i * 16 + (lane >> 2);
            const int p = lane & 3;
            const int ls = p ^ ((row >> 1) & 3);
            const size_t gW = ((size_t)(n0 + row)) * 256 + k0 + ls * 8;
            const int ldsoff = row * 32 + p * 8;
            gl_lds16(Wh + gW, sWh + ldsoff);
            gl_lds16(Wl + gW, sWl + ldsoff);
        }
        __syncthreads();

        const int fr = lane & 15;
        const int fs = lane >> 4;
        bf16x8 ah[4], al[4], wh[4], wl[4];
        #pragma unroll
        for (int f = 0; f < 4; ++f) {
            const int ra = wm + f * 16 + fr;
            const int r7 = ra & 7;
            const uint4 p0 = *(const uint4*)&sA[ra * 32 + ((2 * fs)     ^ r7) * 4];
            const uint4 p1 = *(const uint4*)&sA[ra * 32 + ((2 * fs + 1) ^ r7) * 4];
            const u32 uu[8] = {p0.x, p0.y, p0.z, p0.w, p1.x, p1.y, p1.z, p1.w};
            #pragma unroll
            for (int j = 0; j < 8; ++j) {
                ah[f][j] = (short)(uu[j] & 0xffffu);
                al[f][j] = (short)(uu[j] >> 16);
            }
            const int rw = wn + f * 16 + fr;
            const int ow = rw * 32 + (fs ^ ((rw >> 1) & 3)) * 8;
            wh[f] = *(const bf16x8*)&sWh[ow];
            wl[f] = *(const bf16x8*)&sWl[ow];
        }
        #pragma unroll
        for (int fm = 0; fm < 4; ++fm)
            #pragma unroll
            for (int fn = 0; fn < 4; ++fn) {
                acc[fm][fn] = __builtin_amdgcn_mfma_f32_16x16x32_bf16(ah[fm], wh[fn], acc[fm][fn], 0, 0, 0);
                acc[fm][fn] = __builtin_amdgcn_mfma_f32_16x16x32_bf16(ah[fm], wl[fn], acc[fm][fn], 0, 0, 0);
                acc[fm][fn] = __builtin_amdgcn_mfma_f32_16x16x32_bf16(al[fm], wh[fn], acc[fm][fn], 0, 0, 0);
            }
        __syncthreads();
    }

    const int crow = (lane >> 4) * 4, ccol = lane & 15;
    #pragma unroll
    for (int fm = 0; fm < 4; ++fm)
        #pragma unroll
        for (int fn = 0; fn < 4; ++fn)
            #pragma unroll
            for (int j = 0; j < 4; ++j)
                Cout[(m0 + wm + fm * 16 + crow + j) * 512 + n0 + wn + fn * 16 + ccol] = acc[fm][fn][j];
}

// ---------------------------------------------------------------------------
extern "C" void kernel_launch(void* const* d_in, const int* in_sizes, int n_in,
                              void* d_out, int out_size, void* d_ws, size_t ws_size,
                              hipStream_t stream)
{
    const float* xr      = (const float*)d_in[0];
    const float* xi      = (const float*)d_in[1];
    const float* logAmag = (const float*)d_in[2];
    const float* Aphase  = (const float*)d_in[3];
    const float* Bwr     = (const float*)d_in[4];
    const float* Bwi     = (const float*)d_in[5];
    const float* Cwr     = (const float*)d_in[6];
    const float* Cwi     = (const float*)d_in[7];
    const float* dtw     = (const float*)d_in[8];
    const float* dtb     = (const float*)d_in[9];
    float* out = (float*)d_out;

    // d_out doubles as xcat scratch (exactly 128 MiB), overwritten by gemm_y.
    u16* xch = (u16*)d_out;
    u16* xcl = xch + (size_t)NTOK * 512;

    char* ws = (char*)d_ws;
    size_t off = 0;
    float* bx  = (float*)(ws + off);  off += (size_t)NTOK * 256 * sizeof(float); // 64 MiB (Bx -> packed h)
    float* dtm = (float*)(ws + off);  off += (size_t)NTOK * sizeof(float);
    float* dtp = (float*)(ws + off);  off += (size_t)NTOK * sizeof(float);
    double* cumM = (double*)(ws + off); off += (size_t)NTOK * sizeof(double);
    double* cumP = (double*)(ws + off); off += (size_t)NTOK * sizeof(double);
    float2* Tc = (float2*)(ws + off); off += (size_t)CHUNKS * NCHAN * sizeof(float2);
    float2* Pc = (float2*)(ws + off); off += (size_t)CHUNKS * NCHAN * sizeof(float2);
    u16* WbxH = (u16*)(ws + off); off += 256 * 512 * sizeof(u16);
    u16* WbxL = (u16*)(ws + off); off += 256 * 512 * sizeof(u16);
    u16* WyH  = (u16*)(ws + off); off += 512 * 256 * sizeof(u16);
    u16* WyL  = (u16*)(ws + off); off += 512 * 256 * sizeof(u16);

    prep_weights<<<512, 256, 0, stream>>>(Bwr, Bwi, Cwr, Cwi, WbxH, WbxL, WyH, WyL);
    dt_kernel<<<NTOK / 4, 256, 0, stream>>>(xr, xi, dtw, dtb, dtm, dtp, xch, xcl);
    cumsum_kernel<<<Bdim * Gdim, 256, 0, stream>>>(dtm, dtp, cumM, cumP);
    gemm_bx_mfma<<<dim3(2, 512), 256, 0, stream>>>(xch, xcl, WbxH, WbxL, bx);
    scan_kernel<0><<<dim3(CHUNKS, Bdim * Gdim), 128, 0, stream>>>(
        bx, dtm, cumM, cumP, logAmag, Aphase, Tc, Pc);
    chunk_prefix_kernel<<<(NCHAN + 255) / 256, 256, 0, stream>>>(Tc, Pc);
    scan_kernel<1><<<dim3(CHUNKS, Bdim * Gdim), 128, 0, stream>>>(
        bx, dtm, cumM, cumP, logAmag, Aphase, Tc, Pc);
    gemm_y_mfma<<<dim3(4, 512), 256, 0, stream>>>((const u32*)bx, WyH, WyL, out);
}

// Round 3
// 229.035 us; speedup vs baseline: 2.4847x; 1.3343x over previous
//
#include <hip/hip_runtime.h>
#include <math.h>

#define Bdim 4
#define Sdim 4096
#define Gdim 4
#define Ddim 256
#define Ndim 128
#define NTOK (Bdim*Sdim*Gdim)      // 65536 tokens
#define CHUNKS 64
#define CLEN (Sdim/CHUNKS)         // 64 steps per chunk
#define NCHAN (Bdim*Gdim*Ndim)     // 2048 scan channels

typedef unsigned short u16;
typedef unsigned int   u32;
typedef __attribute__((ext_vector_type(8))) _Float16 f16x8;
typedef __attribute__((ext_vector_type(4))) float f32x4;

#define GLOBAL_AS __attribute__((address_space(1)))
#define LDS_AS    __attribute__((address_space(3)))

__device__ __forceinline__ void gl_lds16(const void* g, void* l) {
    __builtin_amdgcn_global_load_lds((const GLOBAL_AS u32*)g, (LDS_AS u32*)l, 16, 0, 0);
}

union HU { _Float16 h; u16 u; };
__device__ __forceinline__ u16 f2h(float f) { HU c; c.h = (_Float16)f; return c.u; }
__device__ __forceinline__ float h2f(u16 u) { HU c; c.u = u; return (float)c.h; }

// ---------------------------------------------------------------------------
// Weight prep: f16 hi + f16 residual (lo) combined complex matrices.
// Wbx [256 n][512 k]:  n<128 (real out): [Bwr | -Bwi];  n>=128 (imag): [Bwi | Bwr]
// Wy  [512 d][256 k]:  d<256 (yr): [Cwr | -Cwi];        d>=256 (yi):   [Cwi | Cwr]
// ---------------------------------------------------------------------------
__global__ __launch_bounds__(256) void prep_weights(
    const float* __restrict__ Bwr, const float* __restrict__ Bwi,
    const float* __restrict__ Cwr, const float* __restrict__ Cwi,
    u16* __restrict__ WbxH, u16* __restrict__ WbxL,
    u16* __restrict__ WyH,  u16* __restrict__ WyL)
{
    const int idx = blockIdx.x * 256 + threadIdx.x;   // 0..131071
    {
        const int n = idx >> 9, k = idx & 511;
        float v;
        if (n < 128) v = (k < 256) ? Bwr[n * 256 + k] : -Bwi[n * 256 + (k - 256)];
        else         v = (k < 256) ? Bwi[(n - 128) * 256 + k] : Bwr[(n - 128) * 256 + (k - 256)];
        const u16 h = f2h(v);
        WbxH[idx] = h; WbxL[idx] = f2h(v - h2f(h));
    }
    {
        const int d = idx >> 8, k = idx & 255;
        float v;
        if (d < 256) v = (k < 128) ? Cwr[d * 128 + k] : -Cwi[d * 128 + (k - 128)];
        else         v = (k < 128) ? Cwi[(d - 256) * 128 + k] : Cwr[(d - 256) * 128 + (k - 128)];
        const u16 h = f2h(v);
        WyH[idx] = h; WyL[idx] = f2h(v - h2f(h));
    }
}

// ---------------------------------------------------------------------------
// dt projection + xcat f16 emission. One wave per token.
// xcat[tok][512]: k<256 = xr[d], k>=256 = xi[d]  (single f16, in d_out scratch)
// ---------------------------------------------------------------------------
__global__ __launch_bounds__(256) void dt_kernel(
    const float* __restrict__ xr, const float* __restrict__ xi,
    const float* __restrict__ dtw, const float* __restrict__ dtb,
    float* __restrict__ dtm, float* __restrict__ dtp,
    u16* __restrict__ xch)
{
    const int gtid = blockIdx.x * 256 + threadIdx.x;
    const int tok  = gtid >> 6;
    const int lane = gtid & 63;
    if (tok >= NTOK) return;

    const float4 a  = *(const float4*)(xr  + (size_t)tok * Ddim + lane * 4);
    const float4 b4 = *(const float4*)(xi  + (size_t)tok * Ddim + lane * 4);
    const float4 c0 = *(const float4*)(dtw +   0 + lane * 4);
    const float4 d0 = *(const float4*)(dtw + 256 + lane * 4);
    const float4 c1 = *(const float4*)(dtw + 512 + lane * 4);
    const float4 d1 = *(const float4*)(dtw + 768 + lane * 4);

    *(uint2*)(xch + (size_t)tok * 512 + lane * 4) =
        make_uint2((u32)f2h(a.x) | ((u32)f2h(a.y) << 16),
                   (u32)f2h(a.z) | ((u32)f2h(a.w) << 16));
    *(uint2*)(xch + (size_t)tok * 512 + 256 + lane * 4) =
        make_uint2((u32)f2h(b4.x) | ((u32)f2h(b4.y) << 16),
                   (u32)f2h(b4.z) | ((u32)f2h(b4.w) << 16));

    float r0 = a.x*c0.x + a.y*c0.y + a.z*c0.z + a.w*c0.w
             + b4.x*d0.x + b4.y*d0.y + b4.z*d0.z + b4.w*d0.w;
    float r1 = a.x*c1.x + a.y*c1.y + a.z*c1.z + a.w*c1.w
             + b4.x*d1.x + b4.y*d1.y + b4.z*d1.z + b4.w*d1.w;
    #pragma unroll
    for (int off = 32; off; off >>= 1) {
        r0 += __shfl_down(r0, off);
        r1 += __shfl_down(r1, off);
    }
    if (lane == 0) {
        float m = expf(r0 + dtb[0]); m = fminf(fmaxf(m, 1e-4f), 2.0f);
        float p = expf(r1 + dtb[1]); p = fminf(fmaxf(p, 1e-4f), 2.0f);
        dtm[tok] = m;
        dtp[tok] = p;
    }
}

// ---------------------------------------------------------------------------
// f64 cumsum of dt_mag/dt_phase per (b,g). 16 blocks x 256 thr, 16 elem/thr:
// serial local sums -> wave shfl scan -> 4 wave totals via LDS -> emit.
// ---------------------------------------------------------------------------
__global__ __launch_bounds__(256) void cumsum_kernel(
    const float* __restrict__ dtm, const float* __restrict__ dtp,
    double* __restrict__ cumM, double* __restrict__ cumP)
{
    const int bg = blockIdx.x, b = bg >> 2, g = bg & 3;
    const int t = threadIdx.x, lane = t & 63, wid = t >> 6;
    const size_t base = (size_t)b * Sdim * Gdim + g;
    double lm[16], lp[16], sm = 0.0, sp = 0.0;
    #pragma unroll
    for (int j = 0; j < 16; ++j) {
        const size_t tok = base + (size_t)(t * 16 + j) * Gdim;
        sm += (double)dtm[tok]; lm[j] = sm;
        sp += (double)dtp[tok]; lp[j] = sp;
    }
    double im = sm, ip = sp;
    #pragma unroll
    for (int off = 1; off < 64; off <<= 1) {
        double vm = __shfl_up(im, off);
        double vp = __shfl_up(ip, off);
        if (lane >= off) { im += vm; ip += vp; }
    }
    __shared__ double wtm[4], wtp[4];
    if (lane == 63) { wtm[wid] = im; wtp[wid] = ip; }
    __syncthreads();
    double bm = im - sm, bp = ip - sp;     // exclusive base within wave
    for (int w = 0; w < wid; ++w) { bm += wtm[w]; bp += wtp[w]; }
    #pragma unroll
    for (int j = 0; j < 16; ++j) {
        const size_t tok = base + (size_t)(t * 16 + j) * Gdim;
        cumM[tok] = bm + lm[j];
        cumP[tok] = bp + lp[j];
    }
}

// ---------------------------------------------------------------------------
// GEMM 1 (MFMA f16, 2-term): bx[M][256] = xcat[M][512] . Wbx[256][512]^T
// A single f16; W hi+lo. Tile 128x128, BK=32, 4 waves (2x2 of 64x64).
// XCD-chunked block swizzle keeps the 2 n-tiles of an A panel on one XCD.
// ---------------------------------------------------------------------------
__global__ __launch_bounds__(256) void gemm_bx_mfma(
    const u16* __restrict__ Ah,
    const u16* __restrict__ Wh, const u16* __restrict__ Wl,
    u16* __restrict__ Cout)
{
    __shared__ u16 sA[128 * 32], sWh[128 * 32], sWl[128 * 32];
    const int tid = threadIdx.x, wave = tid >> 6, lane = tid & 63;
    const int i0 = blockIdx.x;                       // 0..1023
    const int wg = (i0 & 7) * 128 + (i0 >> 3);       // bijective XCD chunking
    const size_t m0 = (size_t)(wg >> 1) * 128;
    const int n0 = (wg & 1) * 128;
    const int wm = (wave >> 1) * 64, wn = (wave & 1) * 64;
    f32x4 acc[4][4] = {};
    const int srow = lane >> 2, pslot = lane & 3;

    #pragma unroll 1
    for (int k0 = 0; k0 < 512; k0 += 32) {
        #pragma unroll
        for (int i = 0; i < 2; ++i) {
            const int row = wave * 32 + i * 16 + srow;
            const int lslot = pslot ^ ((row >> 1) & 3);     // inverse-swizzled source
            const int ldsoff = row * 32 + pslot * 8;        // linear dest = base + lane*16B
            gl_lds16(Ah + (m0 + row) * 512 + k0 + lslot * 8, sA + ldsoff);
            gl_lds16(Wh + (size_t)(n0 + row) * 512 + k0 + lslot * 8, sWh + ldsoff);
            gl_lds16(Wl + (size_t)(n0 + row) * 512 + k0 + lslot * 8, sWl + ldsoff);
        }
        __syncthreads();

        const int fr = lane & 15, fs = lane >> 4;
        f16x8 a_[4], wh_[4], wl_[4];
        #pragma unroll
        for (int f = 0; f < 4; ++f) {
            const int ra = wm + f * 16 + fr;
            a_[f]  = *(const f16x8*)&sA [ra * 32 + (fs ^ ((ra >> 1) & 3)) * 8];
            const int rw = wn + f * 16 + fr;
            const int ow = rw * 32 + (fs ^ ((rw >> 1) & 3)) * 8;
            wh_[f] = *(const f16x8*)&sWh[ow];
            wl_[f] = *(const f16x8*)&sWl[ow];
        }
        #pragma unroll
        for (int fm = 0; fm < 4; ++fm)
            #pragma unroll
            for (int fn = 0; fn < 4; ++fn) {
                acc[fm][fn] = __builtin_amdgcn_mfma_f32_16x16x32_f16(a_[fm], wh_[fn], acc[fm][fn], 0, 0, 0);
                acc[fm][fn] = __builtin_amdgcn_mfma_f32_16x16x32_f16(a_[fm], wl_[fn], acc[fm][fn], 0, 0, 0);
            }
        __syncthreads();
    }

    const int crow = (lane >> 4) * 4, ccol = lane & 15;
    #pragma unroll
    for (int fm = 0; fm < 4; ++fm)
        #pragma unroll
        for (int fn = 0; fn < 4; ++fn)
            #pragma unroll
            for (int j = 0; j < 4; ++j)
                Cout[(m0 + wm + fm * 16 + crow + j) * 256 + n0 + wn + fn * 16 + ccol] =
                    f2h(acc[fm][fn][j]);
}

// ---------------------------------------------------------------------------
// Chunked scan over f16 bx. PASS 0: chunk totals. PASS 1: emit clipped h as
// f16, in place (element-wise same slot).
// ---------------------------------------------------------------------------
template<int PASS>
__global__ __launch_bounds__(128) void scan_kernel(
    u16* __restrict__ bxh,
    const float* __restrict__ dtm,
    const double* __restrict__ cumM, const double* __restrict__ cumP,
    const float* __restrict__ logAmag, const float* __restrict__ Aphase,
    float2* __restrict__ Tc, const float2* __restrict__ Pc)
{
    const int c = blockIdx.x;
    const int bg = blockIdx.y;
    const int b = bg >> 2, g = bg & 3;
    const int n = threadIdx.x;
    const double nlAd = (double)(-log1pf(expf(logAmag[g * Ndim + n])));
    const double aphd = (double)(Aphase[g * Ndim + n]);

    float Sr = 0.0f, Si = 0.0f;
    if (PASS == 1) {
        const float2 p = Pc[(size_t)c * NCHAN + bg * Ndim + n];
        Sr = p.x; Si = p.y;
    }
    const int s0 = c * CLEN;
    for (int j = 0; j < CLEN; ++j) {
        const int s = s0 + j;
        const size_t tok = ((size_t)(b * Sdim + s)) * Gdim + g;
        const float clr = (float)(nlAd * cumM[tok]);
        const float cli = (float)(aphd * cumP[tok]);
        const float dt = dtm[tok];
        const float e = expf(clr);                 // underflows to 0 like ref
        float sn, cs;
        sincosf(cli, &sn, &cs);
        const float car = e * cs, cai = e * sn;
        const float dr = car + 1e-12f, di = cai;
        const float inv = 1.0f / (dr * dr + di * di);
        const float bxr = h2f(bxh[tok * 256 + n]) * dt;
        const float bxi = h2f(bxh[tok * 256 + 128 + n]) * dt;
        Sr += (bxr * dr + bxi * di) * inv;
        Si += (bxi * dr - bxr * di) * inv;
        if (PASS == 1) {
            const float hr  = car * Sr - cai * Si;
            const float hi2 = car * Si + cai * Sr;
            const float nrm = sqrtf(hr * hr + hi2 * hi2 + 1e-8f);
            const float scl = fminf(nrm, 100.0f) / nrm;
            bxh[tok * 256 + n]       = f2h(hr * scl);
            bxh[tok * 256 + 128 + n] = f2h(hi2 * scl);
        }
    }
    if (PASS == 0) Tc[(size_t)c * NCHAN + bg * Ndim + n] = make_float2(Sr, Si);
}

// ---------------------------------------------------------------------------
// Exclusive prefix over chunk totals.
// ---------------------------------------------------------------------------
__global__ __launch_bounds__(256) void chunk_prefix_kernel(
    const float2* __restrict__ Tc, float2* __restrict__ Pc)
{
    const int ch = blockIdx.x * 256 + threadIdx.x;
    if (ch >= NCHAN) return;
    float Sr = 0.0f, Si = 0.0f;
    for (int c = 0; c < CHUNKS; ++c) {
        const float2 t = Tc[(size_t)c * NCHAN + ch];
        Pc[(size_t)c * NCHAN + ch] = make_float2(Sr, Si);
        Sr += t.x; Si += t.y;
    }
}

// ---------------------------------------------------------------------------
// GEMM 2 (MFMA f16, 2-term): out[M][512] = h[M][256] . Wy[512][256]^T
// A = h single f16 via global_load_lds (no repack). Tile 128x128, BK=32.
// XCD-chunked swizzle keeps the 4 n-tiles of an A panel on one XCD.
// ---------------------------------------------------------------------------
__global__ __launch_bounds__(256) void gemm_y_mfma(
    const u16* __restrict__ Hp,
    const u16* __restrict__ Wh, const u16* __restrict__ Wl,
    float* __restrict__ Cout)
{
    __shared__ u16 sA[128 * 32], sWh[128 * 32], sWl[128 * 32];
    const int tid = threadIdx.x, wave = tid >> 6, lane = tid & 63;
    const int i0 = blockIdx.x;                       // 0..2047
    const int wg = (i0 & 7) * 256 + (i0 >> 3);       // bijective XCD chunking
    const size_t m0 = (size_t)(wg >> 2) * 128;
    const int n0 = (wg & 3) * 128;
    const int wm = (wave >> 1) * 64, wn = (wave & 1) * 64;
    f32x4 acc[4][4] = {};
    const int srow = lane >> 2, pslot = lane & 3;

    #pragma unroll 1
    for (int k0 = 0; k0 < 256; k0 += 32) {
        #pragma unroll
        for (int i = 0; i < 2; ++i) {
            const int row = wave * 32 + i * 16 + srow;
            const int lslot = pslot ^ ((row >> 1) & 3);
            const int ldsoff = row * 32 + pslot * 8;
            gl_lds16(Hp + (m0 + row) * 256 + k0 + lslot * 8, sA + ldsoff);
            gl_lds16(Wh + (size_t)(n0 + row) * 256 + k0 + lslot * 8, sWh + ldsoff);
            gl_lds16(Wl + (size_t)(n0 + row) * 256 + k0 + lslot * 8, sWl + ldsoff);
        }
        __syncthreads();

        const int fr = lane & 15, fs = lane >> 4;
        f16x8 a_[4], wh_[4], wl_[4];
        #pragma unroll
        for (int f = 0; f < 4; ++f) {
            const int ra = wm + f * 16 + fr;
            a_[f]  = *(const f16x8*)&sA [ra * 32 + (fs ^ ((ra >> 1) & 3)) * 8];
            const int rw = wn + f * 16 + fr;
            const int ow = rw * 32 + (fs ^ ((rw >> 1) & 3)) * 8;
            wh_[f] = *(const f16x8*)&sWh[ow];
            wl_[f] = *(const f16x8*)&sWl[ow];
        }
        #pragma unroll
        for (int fm = 0; fm < 4; ++fm)
            #pragma unroll
            for (int fn = 0; fn < 4; ++fn) {
                acc[fm][fn] = __builtin_amdgcn_mfma_f32_16x16x32_f16(a_[fm], wh_[fn], acc[fm][fn], 0, 0, 0);
                acc[fm][fn] = __builtin_amdgcn_mfma_f32_16x16x32_f16(a_[fm], wl_[fn], acc[fm][fn], 0, 0, 0);
            }
        __syncthreads();
    }

    const int crow = (lane >> 4) * 4, ccol = lane & 15;
    #pragma unroll
    for (int fm = 0; fm < 4; ++fm)
        #pragma unroll
        for (int fn = 0; fn < 4; ++fn)
            #pragma unroll
            for (int j = 0; j < 4; ++j)
                Cout[(m0 + wm + fm * 16 + crow + j) * 512 + n0 + wn + fn * 16 + ccol] =
                    acc[fm][fn][j];
}

// ---------------------------------------------------------------------------
extern "C" void kernel_launch(void* const* d_in, const int* in_sizes, int n_in,
                              void* d_out, int out_size, void* d_ws, size_t ws_size,
                              hipStream_t stream)
{
    const float* xr      = (const float*)d_in[0];
    const float* xi      = (const float*)d_in[1];
    const float* logAmag = (const float*)d_in[2];
    const float* Aphase  = (const float*)d_in[3];
    const float* Bwr     = (const float*)d_in[4];
    const float* Bwi     = (const float*)d_in[5];
    const float* Cwr     = (const float*)d_in[6];
    const float* Cwi     = (const float*)d_in[7];
    const float* dtw     = (const float*)d_in[8];
    const float* dtb     = (const float*)d_in[9];
    float* out = (float*)d_out;

    // d_out doubles as xcat scratch (64 MiB of its 128 MiB), fully overwritten
    // by gemm_y at the end of every launch.
    u16* xch = (u16*)d_out;

    char* ws = (char*)d_ws;
    size_t off = 0;
    u16* bxh  = (u16*)(ws + off);  off += (size_t)NTOK * 256 * sizeof(u16);  // 32 MiB (Bx -> h, f16)
    float* dtm = (float*)(ws + off);  off += (size_t)NTOK * sizeof(float);
    float* dtp = (float*)(ws + off);  off += (size_t)NTOK * sizeof(float);
    double* cumM = (double*)(ws + off); off += (size_t)NTOK * sizeof(double);
    double* cumP = (double*)(ws + off); off += (size_t)NTOK * sizeof(double);
    float2* Tc = (float2*)(ws + off); off += (size_t)CHUNKS * NCHAN * sizeof(float2);
    float2* Pc = (float2*)(ws + off); off += (size_t)CHUNKS * NCHAN * sizeof(float2);
    u16* WbxH = (u16*)(ws + off); off += 256 * 512 * sizeof(u16);
    u16* WbxL = (u16*)(ws + off); off += 256 * 512 * sizeof(u16);
    u16* WyH  = (u16*)(ws + off); off += 512 * 256 * sizeof(u16);
    u16* WyL  = (u16*)(ws + off); off += 512 * 256 * sizeof(u16);

    prep_weights<<<512, 256, 0, stream>>>(Bwr, Bwi, Cwr, Cwi, WbxH, WbxL, WyH, WyL);
    dt_kernel<<<NTOK / 4, 256, 0, stream>>>(xr, xi, dtw, dtb, dtm, dtp, xch);
    cumsum_kernel<<<Bdim * Gdim, 256, 0, stream>>>(dtm, dtp, cumM, cumP);
    gemm_bx_mfma<<<1024, 256, 0, stream>>>(xch, WbxH, WbxL, bxh);
    scan_kernel<0><<<dim3(CHUNKS, Bdim * Gdim), 128, 0, stream>>>(
        bxh, dtm, cumM, cumP, logAmag, Aphase, Tc, Pc);
    chunk_prefix_kernel<<<(NCHAN + 255) / 256, 256, 0, stream>>>(Tc, Pc);
    scan_kernel<1><<<dim3(CHUNKS, Bdim * Gdim), 128, 0, stream>>>(
        bxh, dtm, cumM, cumP, logAmag, Aphase, Tc, Pc);
    gemm_y_mfma<<<2048, 256, 0, stream>>>(bxh, WyH, WyL, out);
}

// Round 4
// 200.391 us; speedup vs baseline: 2.8399x; 1.1429x over previous
//
#include <hip/hip_runtime.h>
#include <math.h>

#define Bdim 4
#define Sdim 4096
#define Gdim 4
#define Ddim 256
#define Ndim 128
#define NTOK (Bdim*Sdim*Gdim)      // 65536 tokens
#define CHUNKS 64
#define CLEN (Sdim/CHUNKS)         // 64 steps per chunk
#define NCHAN (Bdim*Gdim*Ndim)     // 2048 scan channels

typedef unsigned short u16;
typedef unsigned int   u32;
typedef __attribute__((ext_vector_type(8))) _Float16 f16x8;
typedef __attribute__((ext_vector_type(4))) float f32x4;

#define GLOBAL_AS __attribute__((address_space(1)))
#define LDS_AS    __attribute__((address_space(3)))

__device__ __forceinline__ void gl_lds16(const void* g, void* l) {
    __builtin_amdgcn_global_load_lds((const GLOBAL_AS u32*)g, (LDS_AS u32*)l, 16, 0, 0);
}

union HU { _Float16 h; u16 u; };
__device__ __forceinline__ u16 f2h(float f) { HU c; c.h = (_Float16)f; return c.u; }
__device__ __forceinline__ float h2f(u16 u) { HU c; c.u = u; return (float)c.h; }

// ---------------------------------------------------------------------------
// Weight prep (single f16 term for GEMM weights + dt tile hi/lo).
// WbxH [256 n][512 k]: n<128: [Bwr | -Bwi]; n>=128: [Bwi | Bwr]
// WyH  [512 d][256 k]: d<256: [Cwr | -Cwi]; d>=256: [Cwi | Cwr]
// dtT  [64 kc][16 col][8 kk] f16: col0=dtw0_hi, col1=dtw1_hi,
//                                 col2=dtw0_lo, col3=dtw1_lo, col4-15=0
// ---------------------------------------------------------------------------
__global__ __launch_bounds__(256) void prep_weights(
    const float* __restrict__ Bwr, const float* __restrict__ Bwi,
    const float* __restrict__ Cwr, const float* __restrict__ Cwi,
    const float* __restrict__ dtw,
    u16* __restrict__ WbxH, u16* __restrict__ WyH, u16* __restrict__ dtT)
{
    const int idx = blockIdx.x * 256 + threadIdx.x;   // 0..131071
    {
        const int n = idx >> 9, k = idx & 511;
        float v;
        if (n < 128) v = (k < 256) ? Bwr[n * 256 + k] : -Bwi[n * 256 + (k - 256)];
        else         v = (k < 256) ? Bwi[(n - 128) * 256 + k] : Bwr[(n - 128) * 256 + (k - 256)];
        WbxH[idx] = f2h(v);
    }
    {
        const int d = idx >> 8, k = idx & 255;
        float v;
        if (d < 256) v = (k < 128) ? Cwr[d * 128 + k] : -Cwi[d * 128 + (k - 128)];
        else         v = (k < 128) ? Cwi[(d - 256) * 128 + k] : Cwr[(d - 256) * 128 + (k - 128)];
        WyH[idx] = f2h(v);
    }
    if (idx < 8192) {
        const int col = (idx >> 3) & 15;
        const int k = ((idx >> 7) << 3) | (idx & 7);   // kc*8 + kk
        u16 r = 0;
        if (col == 0) r = f2h(dtw[k]);
        else if (col == 1) r = f2h(dtw[512 + k]);
        else if (col == 2) { const u16 hh = f2h(dtw[k]);       r = f2h(dtw[k] - h2f(hh)); }
        else if (col == 3) { const u16 hh = f2h(dtw[512 + k]); r = f2h(dtw[512 + k] - h2f(hh)); }
        dtT[idx] = r;
    }
}

// ---------------------------------------------------------------------------
// Fused GEMM 1 + dt projection.
// bx[M][256] = (xcat[M][512] . Wbx[256][512]^T) * dt_mag[M]   (f16 out)
// dt logits via extra MFMAs against the dt tile (cols 0-3), computed by the
// wn==0 waves; dt_mag/dt_phase written to global by n0==0 blocks.
// A reg-staged fp32->f16 with both-sides XOR slot swizzle.
// ---------------------------------------------------------------------------
__global__ __launch_bounds__(256) void gemm_bx_fused(
    const float* __restrict__ xr, const float* __restrict__ xi,
    const u16* __restrict__ Wh, const u16* __restrict__ dtT,
    const float* __restrict__ dtb,
    u16* __restrict__ bxh, float* __restrict__ dtm, float* __restrict__ dtp)
{
    __shared__ u16 sA[128 * 32], sWh[128 * 32], sDT[8192];
    const int tid = threadIdx.x, wave = tid >> 6, lane = tid & 63;
    const int i0 = blockIdx.x;                       // 0..1023
    const int wg = (i0 & 7) * 128 + (i0 >> 3);       // bijective XCD chunking
    const size_t m0 = (size_t)(wg >> 1) * 128;
    const int n0 = (wg & 1) * 128;
    const int wm = (wave >> 1) * 64, wn = (wave & 1) * 64;
    f32x4 acc[4][4] = {};
    f32x4 dacc[4] = {};
    const int srow = lane >> 2, pslot = lane & 3;

    for (int i = tid; i < 4096; i += 256)            // dt tile -> LDS (once)
        ((u32*)sDT)[i] = ((const u32*)dtT)[i];

    const int ar  = tid >> 1;                        // A-staging row 0..127
    const int acb = (tid & 1) * 16;                  // col base within 32
    const int asl = (tid & 1) * 2;                   // logical slot base
    const int aswz = (ar >> 1) & 3;

    #pragma unroll 1
    for (int k0 = 0; k0 < 512; k0 += 32) {
        {   // A: reg-stage fp32 -> f16 (swizzled ds_write)
            const float* xsrc = (k0 < 256) ? xr : xi;
            const float* src = xsrc + (m0 + ar) * 256 + (k0 & 255) + acb;
            const float4 v0 = *(const float4*)(src);
            const float4 v1 = *(const float4*)(src + 4);
            const float4 v2 = *(const float4*)(src + 8);
            const float4 v3 = *(const float4*)(src + 12);
            f16x8 p0, p1;
            p0[0]=(_Float16)v0.x; p0[1]=(_Float16)v0.y; p0[2]=(_Float16)v0.z; p0[3]=(_Float16)v0.w;
            p0[4]=(_Float16)v1.x; p0[5]=(_Float16)v1.y; p0[6]=(_Float16)v1.z; p0[7]=(_Float16)v1.w;
            p1[0]=(_Float16)v2.x; p1[1]=(_Float16)v2.y; p1[2]=(_Float16)v2.z; p1[3]=(_Float16)v2.w;
            p1[4]=(_Float16)v3.x; p1[5]=(_Float16)v3.y; p1[6]=(_Float16)v3.z; p1[7]=(_Float16)v3.w;
            *(f16x8*)&sA[ar * 32 + ((asl    ) ^ aswz) * 8] = p0;
            *(f16x8*)&sA[ar * 32 + ((asl + 1) ^ aswz) * 8] = p1;
        }
        #pragma unroll
        for (int i = 0; i < 2; ++i) {                // W via global_load_lds
            const int row = wave * 32 + i * 16 + srow;
            const int lslot = pslot ^ ((row >> 1) & 3);
            gl_lds16(Wh + (size_t)(n0 + row) * 512 + k0 + lslot * 8,
                     sWh + row * 32 + pslot * 8);
        }
        __syncthreads();

        const int fr = lane & 15, fs = lane >> 4;
        f16x8 a_[4], w_[4];
        #pragma unroll
        for (int f = 0; f < 4; ++f) {
            const int ra = wm + f * 16 + fr;
            a_[f] = *(const f16x8*)&sA [ra * 32 + (fs ^ ((ra >> 1) & 3)) * 8];
            const int rw = wn + f * 16 + fr;
            w_[f] = *(const f16x8*)&sWh[rw * 32 + (fs ^ ((rw >> 1) & 3)) * 8];
        }
        #pragma unroll
        for (int fm = 0; fm < 4; ++fm)
            #pragma unroll
            for (int fn = 0; fn < 4; ++fn)
                acc[fm][fn] = __builtin_amdgcn_mfma_f32_16x16x32_f16(a_[fm], w_[fn], acc[fm][fn], 0, 0, 0);
        if ((wave & 1) == 0) {                       // dt logits (waves 0,2)
            const f16x8 df = *(const f16x8*)&sDT[((k0 >> 3) + fs) * 128 + fr * 8];
            #pragma unroll
            for (int fm = 0; fm < 4; ++fm)
                dacc[fm] = __builtin_amdgcn_mfma_f32_16x16x32_f16(a_[fm], df, dacc[fm], 0, 0, 0);
        }
        __syncthreads();
    }

    // dt epilogue: combine hi+lo cols, exp/clip, share via LDS
    float* dtL  = (float*)sA;           // [4][128] logit parts
    float* dtmL = (float*)sWh;          // [128]
    float* dtpL = dtmL + 128;
    if ((wave & 1) == 0) {
        const int col = lane & 15;
        const int rbase = (lane >> 4) * 4;
        if (col < 4) {
            #pragma unroll
            for (int fm = 0; fm < 4; ++fm)
                #pragma unroll
                for (int j = 0; j < 4; ++j)
                    dtL[col * 128 + wm + fm * 16 + rbase + j] = dacc[fm][j];
        }
    }
    __syncthreads();
    if (tid < 128) {
        const float l0 = dtL[tid]       + dtL[256 + tid];
        const float l1 = dtL[128 + tid] + dtL[384 + tid];
        float m = expf(l0 + dtb[0]); m = fminf(fmaxf(m, 1e-4f), 2.0f);
        float p = expf(l1 + dtb[1]); p = fminf(fmaxf(p, 1e-4f), 2.0f);
        dtmL[tid] = m; dtpL[tid] = p;
        if (n0 == 0) { dtm[m0 + tid] = m; dtp[m0 + tid] = p; }
    }
    __syncthreads();

    const int crow = (lane >> 4) * 4, ccol = lane & 15;
    #pragma unroll
    for (int fm = 0; fm < 4; ++fm)
        #pragma unroll
        for (int fn = 0; fn < 4; ++fn)
            #pragma unroll
            for (int j = 0; j < 4; ++j) {
                const int rl = wm + fm * 16 + crow + j;
                bxh[(m0 + rl) * 256 + n0 + wn + fn * 16 + ccol] =
                    f2h(acc[fm][fn][j] * dtmL[rl]);
            }
}

// ---------------------------------------------------------------------------
// f64 cumsum of dt_mag/dt_phase per (b,g).
// ---------------------------------------------------------------------------
__global__ __launch_bounds__(256) void cumsum_kernel(
    const float* __restrict__ dtm, const float* __restrict__ dtp,
    double* __restrict__ cumM, double* __restrict__ cumP)
{
    const int bg = blockIdx.x, b = bg >> 2, g = bg & 3;
    const int t = threadIdx.x, lane = t & 63, wid = t >> 6;
    const size_t base = (size_t)b * Sdim * Gdim + g;
    double lm[16], lp[16], sm = 0.0, sp = 0.0;
    #pragma unroll
    for (int j = 0; j < 16; ++j) {
        const size_t tok = base + (size_t)(t * 16 + j) * Gdim;
        sm += (double)dtm[tok]; lm[j] = sm;
        sp += (double)dtp[tok]; lp[j] = sp;
    }
    double im = sm, ip = sp;
    #pragma unroll
    for (int off = 1; off < 64; off <<= 1) {
        double vm = __shfl_up(im, off);
        double vp = __shfl_up(ip, off);
        if (lane >= off) { im += vm; ip += vp; }
    }
    __shared__ double wtm[4], wtp[4];
    if (lane == 63) { wtm[wid] = im; wtp[wid] = ip; }
    __syncthreads();
    double bm = im - sm, bp = ip - sp;
    for (int w = 0; w < wid; ++w) { bm += wtm[w]; bp += wtp[w]; }
    #pragma unroll
    for (int j = 0; j < 16; ++j) {
        const size_t tok = base + (size_t)(t * 16 + j) * Gdim;
        cumM[tok] = bm + lm[j];
        cumP[tok] = bp + lp[j];
    }
}

// ---------------------------------------------------------------------------
// Chunked scan over f16 bx (dt already folded in).
// PASS 0: chunk totals. PASS 1: emit clipped h (f16, in place).
// ---------------------------------------------------------------------------
template<int PASS>
__global__ __launch_bounds__(128) void scan_kernel(
    u16* __restrict__ bxh,
    const double* __restrict__ cumM, const double* __restrict__ cumP,
    const float* __restrict__ logAmag, const float* __restrict__ Aphase,
    float2* __restrict__ Tc, const float2* __restrict__ Pc)
{
    const int c = blockIdx.x;
    const int bg = blockIdx.y;
    const int b = bg >> 2, g = bg & 3;
    const int n = threadIdx.x;
    const double nlAd = (double)(-log1pf(expf(logAmag[g * Ndim + n])));
    const double aphd = (double)(Aphase[g * Ndim + n]);

    float Sr = 0.0f, Si = 0.0f;
    if (PASS == 1) {
        const float2 p = Pc[(size_t)c * NCHAN + bg * Ndim + n];
        Sr = p.x; Si = p.y;
    }
    const int s0 = c * CLEN;
    for (int j = 0; j < CLEN; ++j) {
        const int s = s0 + j;
        const size_t tok = ((size_t)(b * Sdim + s)) * Gdim + g;
        const float clr = (float)(nlAd * cumM[tok]);
        const float cli = (float)(aphd * cumP[tok]);
        const float e = expf(clr);                 // underflows to 0 like ref
        float sn, cs;
        sincosf(cli, &sn, &cs);
        const float car = e * cs, cai = e * sn;
        const float dr = car + 1e-12f, di = cai;
        const float inv = 1.0f / (dr * dr + di * di);
        const float bxr = h2f(bxh[tok * 256 + n]);
        const float bxi = h2f(bxh[tok * 256 + 128 + n]);
        Sr += (bxr * dr + bxi * di) * inv;
        Si += (bxi * dr - bxr * di) * inv;
        if (PASS == 1) {
            const float hr  = car * Sr - cai * Si;
            const float hi2 = car * Si + cai * Sr;
            const float nrm = sqrtf(hr * hr + hi2 * hi2 + 1e-8f);
            const float scl = fminf(nrm, 100.0f) / nrm;
            bxh[tok * 256 + n]       = f2h(hr * scl);
            bxh[tok * 256 + 128 + n] = f2h(hi2 * scl);
        }
    }
    if (PASS == 0) Tc[(size_t)c * NCHAN + bg * Ndim + n] = make_float2(Sr, Si);
}

// ---------------------------------------------------------------------------
// Exclusive prefix over chunk totals.
// ---------------------------------------------------------------------------
__global__ __launch_bounds__(256) void chunk_prefix_kernel(
    const float2* __restrict__ Tc, float2* __restrict__ Pc)
{
    const int ch = blockIdx.x * 256 + threadIdx.x;
    if (ch >= NCHAN) return;
    float Sr = 0.0f, Si = 0.0f;
    for (int c = 0; c < CHUNKS; ++c) {
        const float2 t = Tc[(size_t)c * NCHAN + ch];
        Pc[(size_t)c * NCHAN + ch] = make_float2(Sr, Si);
        Sr += t.x; Si += t.y;
    }
}

// ---------------------------------------------------------------------------
// GEMM 2 (MFMA f16, single term): out[M][512] = h[M][256] . Wy[512][256]^T
// ---------------------------------------------------------------------------
__global__ __launch_bounds__(256) void gemm_y_mfma(
    const u16* __restrict__ Hp,
    const u16* __restrict__ Wh,
    float* __restrict__ Cout)
{
    __shared__ u16 sA[128 * 32], sWh[128 * 32];
    const int tid = threadIdx.x, wave = tid >> 6, lane = tid & 63;
    const int i0 = blockIdx.x;                       // 0..2047
    const int wg = (i0 & 7) * 256 + (i0 >> 3);       // bijective XCD chunking
    const size_t m0 = (size_t)(wg >> 2) * 128;
    const int n0 = (wg & 3) * 128;
    const int wm = (wave >> 1) * 64, wn = (wave & 1) * 64;
    f32x4 acc[4][4] = {};
    const int srow = lane >> 2, pslot = lane & 3;

    #pragma unroll 1
    for (int k0 = 0; k0 < 256; k0 += 32) {
        #pragma unroll
        for (int i = 0; i < 2; ++i) {
            const int row = wave * 32 + i * 16 + srow;
            const int lslot = pslot ^ ((row >> 1) & 3);
            const int ldsoff = row * 32 + pslot * 8;
            gl_lds16(Hp + (m0 + row) * 256 + k0 + lslot * 8, sA + ldsoff);
            gl_lds16(Wh + (size_t)(n0 + row) * 256 + k0 + lslot * 8, sWh + ldsoff);
        }
        __syncthreads();

        const int fr = lane & 15, fs = lane >> 4;
        f16x8 a_[4], w_[4];
        #pragma unroll
        for (int f = 0; f < 4; ++f) {
            const int ra = wm + f * 16 + fr;
            a_[f] = *(const f16x8*)&sA [ra * 32 + (fs ^ ((ra >> 1) & 3)) * 8];
            const int rw = wn + f * 16 + fr;
            w_[f] = *(const f16x8*)&sWh[rw * 32 + (fs ^ ((rw >> 1) & 3)) * 8];
        }
        #pragma unroll
        for (int fm = 0; fm < 4; ++fm)
            #pragma unroll
            for (int fn = 0; fn < 4; ++fn)
                acc[fm][fn] = __builtin_amdgcn_mfma_f32_16x16x32_f16(a_[fm], w_[fn], acc[fm][fn], 0, 0, 0);
        __syncthreads();
    }

    const int crow = (lane >> 4) * 4, ccol = lane & 15;
    #pragma unroll
    for (int fm = 0; fm < 4; ++fm)
        #pragma unroll
        for (int fn = 0; fn < 4; ++fn)
            #pragma unroll
            for (int j = 0; j < 4; ++j)
                Cout[(m0 + wm + fm * 16 + crow + j) * 512 + n0 + wn + fn * 16 + ccol] =
                    acc[fm][fn][j];
}

// ---------------------------------------------------------------------------
extern "C" void kernel_launch(void* const* d_in, const int* in_sizes, int n_in,
                              void* d_out, int out_size, void* d_ws, size_t ws_size,
                              hipStream_t stream)
{
    const float* xr      = (const float*)d_in[0];
    const float* xi      = (const float*)d_in[1];
    const float* logAmag = (const float*)d_in[2];
    const float* Aphase  = (const float*)d_in[3];
    const float* Bwr     = (const float*)d_in[4];
    const float* Bwi     = (const float*)d_in[5];
    const float* Cwr     = (const float*)d_in[6];
    const float* Cwi     = (const float*)d_in[7];
    const float* dtw     = (const float*)d_in[8];
    const float* dtb     = (const float*)d_in[9];
    float* out = (float*)d_out;

    char* ws = (char*)d_ws;
    size_t off = 0;
    u16* bxh  = (u16*)(ws + off);  off += (size_t)NTOK * 256 * sizeof(u16);  // 32 MiB
    float* dtm = (float*)(ws + off);  off += (size_t)NTOK * sizeof(float);
    float* dtp = (float*)(ws + off);  off += (size_t)NTOK * sizeof(float);
    double* cumM = (double*)(ws + off); off += (size_t)NTOK * sizeof(double);
    double* cumP = (double*)(ws + off); off += (size_t)NTOK * sizeof(double);
    float2* Tc = (float2*)(ws + off); off += (size_t)CHUNKS * NCHAN * sizeof(float2);
    float2* Pc = (float2*)(ws + off); off += (size_t)CHUNKS * NCHAN * sizeof(float2);
    u16* WbxH = (u16*)(ws + off); off += 256 * 512 * sizeof(u16);
    u16* WyH  = (u16*)(ws + off); off += 512 * 256 * sizeof(u16);
    u16* dtT  = (u16*)(ws + off); off += 8192 * sizeof(u16);

    prep_weights<<<512, 256, 0, stream>>>(Bwr, Bwi, Cwr, Cwi, dtw, WbxH, WyH, dtT);
    gemm_bx_fused<<<1024, 256, 0, stream>>>(xr, xi, WbxH, dtT, dtb, bxh, dtm, dtp);
    cumsum_kernel<<<Bdim * Gdim, 256, 0, stream>>>(dtm, dtp, cumM, cumP);
    scan_kernel<0><<<dim3(CHUNKS, Bdim * Gdim), 128, 0, stream>>>(
        bxh, cumM, cumP, logAmag, Aphase, Tc, Pc);
    chunk_prefix_kernel<<<(NCHAN + 255) / 256, 256, 0, stream>>>(Tc, Pc);
    scan_kernel<1><<<dim3(CHUNKS, Bdim * Gdim), 128, 0, stream>>>(
        bxh, cumM, cumP, logAmag, Aphase, Tc, Pc);
    gemm_y_mfma<<<2048, 256, 0, stream>>>(bxh, WyH, out);
}

// Round 5
// 170.563 us; speedup vs baseline: 3.3365x; 1.1749x over previous
//
#include <hip/hip_runtime.h>
#include <math.h>

#define Bdim 4
#define Sdim 4096
#define Gdim 4
#define Ddim 256
#define Ndim 128
#define NTOK (Bdim*Sdim*Gdim)      // 65536 tokens
#define CHUNKS 128
#define CLEN (Sdim/CHUNKS)         // 32 steps per chunk
#define NCHAN (Bdim*Gdim*Ndim)     // 2048 scan channels

typedef unsigned short u16;
typedef unsigned int   u32;
typedef __attribute__((ext_vector_type(8))) _Float16 f16x8;
typedef __attribute__((ext_vector_type(4))) _Float16 f16x4;
typedef __attribute__((ext_vector_type(4))) float f32x4;

#define GLOBAL_AS __attribute__((address_space(1)))
#define LDS_AS    __attribute__((address_space(3)))

__device__ __forceinline__ void gl_lds16(const void* g, void* l) {
    __builtin_amdgcn_global_load_lds((const GLOBAL_AS u32*)g, (LDS_AS u32*)l, 16, 0, 0);
}

union HU { _Float16 h; u16 u; };
__device__ __forceinline__ u16 f2h(float f) { HU c; c.h = (_Float16)f; return c.u; }
__device__ __forceinline__ float h2f(u16 u) { HU c; c.u = u; return (float)c.h; }

// ---------------------------------------------------------------------------
// Weight prep (single f16 term).
// WbxH [256 n][512 k]: n<128: [Bwr | -Bwi]; n>=128: [Bwi | Bwr]
// WyH  [512 d][256 k]: d<256: [Cwr | -Cwi]; d>=256: [Cwi | Cwr]
// ---------------------------------------------------------------------------
__global__ __launch_bounds__(256) void prep_weights(
    const float* __restrict__ Bwr, const float* __restrict__ Bwi,
    const float* __restrict__ Cwr, const float* __restrict__ Cwi,
    u16* __restrict__ WbxH, u16* __restrict__ WyH)
{
    const int idx = blockIdx.x * 256 + threadIdx.x;   // 0..131071
    {
        const int n = idx >> 9, k = idx & 511;
        float v;
        if (n < 128) v = (k < 256) ? Bwr[n * 256 + k] : -Bwi[n * 256 + (k - 256)];
        else         v = (k < 256) ? Bwi[(n - 128) * 256 + k] : Bwr[(n - 128) * 256 + (k - 256)];
        WbxH[idx] = f2h(v);
    }
    {
        const int d = idx >> 8, k = idx & 255;
        float v;
        if (d < 256) v = (k < 128) ? Cwr[d * 128 + k] : -Cwi[d * 128 + (k - 128)];
        else         v = (k < 128) ? Cwi[(d - 256) * 128 + k] : Cwr[(d - 256) * 128 + (k - 128)];
        WyH[idx] = f2h(v);
    }
}

// ---------------------------------------------------------------------------
// Fused GEMM 1 + fp32 dt projection.
// bx[M][256] = (xcat[M][512] . Wbx[256][512]^T) * dt_mag[M]   (f16 out)
// dt logits accumulated in fp32 DURING A-staging (x read once, coalesced
// 128B segments); 8-lane shfl reduce at the end. dt_mag/dt_phase written
// by n0==0 blocks.
// ---------------------------------------------------------------------------
__global__ __launch_bounds__(256) void gemm_bx_fused(
    const float* __restrict__ xr, const float* __restrict__ xi,
    const u16* __restrict__ Wh, const float* __restrict__ dtw,
    const float* __restrict__ dtb,
    u16* __restrict__ bxh, float* __restrict__ dtm, float* __restrict__ dtp)
{
    __shared__ u16 sA[128 * 32], sWh[128 * 32];
    __shared__ float sdtw[1024];          // dt_w[2][512]
    __shared__ float2 sDtL[128];          // per-row (logit0, logit1)
    __shared__ float  sDtM[128];          // per-row dt_mag
    const int tid = threadIdx.x, wave = tid >> 6, lane = tid & 63;
    const int i0 = blockIdx.x;                       // 0..1023
    const int wg = (i0 & 7) * 128 + (i0 >> 3);       // bijective XCD chunking
    const size_t m0 = (size_t)(wg >> 1) * 128;
    const int n0 = (wg & 1) * 128;
    const int wm = (wave >> 1) * 64, wn = (wave & 1) * 64;
    f32x4 acc[4][4] = {};
    float dl0[4] = {}, dl1[4] = {};       // dt logit partials (4 row-groups)
    const int srow = lane >> 2, pslot = lane & 3;

    for (int i = tid; i < 1024; i += 256) sdtw[i] = dtw[i];

    const int arow = tid >> 3;            // 0..31 (row within group of 32)
    const int acol = (tid & 7) * 4;       // 0,4,...,28 within 32-col window
    const int asl  = acol >> 3;           // logical slot
    const int asub = acol & 7;            // sub-slot offset (0 or 4)

    #pragma unroll 1
    for (int k0 = 0; k0 < 512; k0 += 32) {
        {   // A: coalesced fp32 load -> f16 ds_write (swizzled) + fp32 dt dot
            const float* xsrc = (k0 < 256) ? xr : xi;
            const int kk = (k0 & 255) + acol;
            const float4 w0v = *(const float4*)&sdtw[k0 + acol];
            const float4 w1v = *(const float4*)&sdtw[512 + k0 + acol];
            #pragma unroll
            for (int i = 0; i < 4; ++i) {
                const int row = arow + 32 * i;
                const float4 v = *(const float4*)(xsrc + (m0 + row) * 256 + kk);
                dl0[i] += v.x * w0v.x + v.y * w0v.y + v.z * w0v.z + v.w * w0v.w;
                dl1[i] += v.x * w1v.x + v.y * w1v.y + v.z * w1v.z + v.w * w1v.w;
                f16x4 p;
                p[0] = (_Float16)v.x; p[1] = (_Float16)v.y;
                p[2] = (_Float16)v.z; p[3] = (_Float16)v.w;
                *(f16x4*)&sA[row * 32 + (asl ^ ((row >> 1) & 3)) * 8 + asub] = p;
            }
        }
        #pragma unroll
        for (int i = 0; i < 2; ++i) {                // W via global_load_lds
            const int row = wave * 32 + i * 16 + srow;
            const int lslot = pslot ^ ((row >> 1) & 3);
            gl_lds16(Wh + (size_t)(n0 + row) * 512 + k0 + lslot * 8,
                     sWh + row * 32 + pslot * 8);
        }
        __syncthreads();

        const int fr = lane & 15, fs = lane >> 4;
        f16x8 a_[4], w_[4];
        #pragma unroll
        for (int f = 0; f < 4; ++f) {
            const int ra = wm + f * 16 + fr;
            a_[f] = *(const f16x8*)&sA [ra * 32 + (fs ^ ((ra >> 1) & 3)) * 8];
            const int rw = wn + f * 16 + fr;
            w_[f] = *(const f16x8*)&sWh[rw * 32 + (fs ^ ((rw >> 1) & 3)) * 8];
        }
        #pragma unroll
        for (int fm = 0; fm < 4; ++fm)
            #pragma unroll
            for (int fn = 0; fn < 4; ++fn)
                acc[fm][fn] = __builtin_amdgcn_mfma_f32_16x16x32_f16(a_[fm], w_[fn], acc[fm][fn], 0, 0, 0);
        __syncthreads();
    }

    // dt epilogue: butterfly-reduce logits within each 8-lane row group
    #pragma unroll
    for (int lvl = 1; lvl < 8; lvl <<= 1) {
        #pragma unroll
        for (int i = 0; i < 4; ++i) {
            dl0[i] += __shfl_xor(dl0[i], lvl);
            dl1[i] += __shfl_xor(dl1[i], lvl);
        }
    }
    if ((tid & 7) == 0) {
        #pragma unroll
        for (int i = 0; i < 4; ++i)
            sDtL[arow + 32 * i] = make_float2(dl0[i], dl1[i]);
    }
    __syncthreads();
    if (tid < 128) {
        const float2 l = sDtL[tid];
        float m = expf(l.x + dtb[0]); m = fminf(fmaxf(m, 1e-4f), 2.0f);
        float p = expf(l.y + dtb[1]); p = fminf(fmaxf(p, 1e-4f), 2.0f);
        sDtM[tid] = m;
        if (n0 == 0) { dtm[m0 + tid] = m; dtp[m0 + tid] = p; }
    }
    __syncthreads();

    const int crow = (lane >> 4) * 4, ccol = lane & 15;
    #pragma unroll
    for (int fm = 0; fm < 4; ++fm)
        #pragma unroll
        for (int fn = 0; fn < 4; ++fn)
            #pragma unroll
            for (int j = 0; j < 4; ++j) {
                const int rl = wm + fm * 16 + crow + j;
                bxh[(m0 + rl) * 256 + n0 + wn + fn * 16 + ccol] =
                    f2h(acc[fm][fn][j] * sDtM[rl]);
            }
}

// ---------------------------------------------------------------------------
// f64 cumsum of dt_mag/dt_phase per (b,g).
// ---------------------------------------------------------------------------
__global__ __launch_bounds__(256) void cumsum_kernel(
    const float* __restrict__ dtm, const float* __restrict__ dtp,
    double* __restrict__ cumM, double* __restrict__ cumP)
{
    const int bg = blockIdx.x, b = bg >> 2, g = bg & 3;
    const int t = threadIdx.x, lane = t & 63, wid = t >> 6;
    const size_t base = (size_t)b * Sdim * Gdim + g;
    double lm[16], lp[16], sm = 0.0, sp = 0.0;
    #pragma unroll
    for (int j = 0; j < 16; ++j) {
        const size_t tok = base + (size_t)(t * 16 + j) * Gdim;
        sm += (double)dtm[tok]; lm[j] = sm;
        sp += (double)dtp[tok]; lp[j] = sp;
    }
    double im = sm, ip = sp;
    #pragma unroll
    for (int off = 1; off < 64; off <<= 1) {
        double vm = __shfl_up(im, off);
        double vp = __shfl_up(ip, off);
        if (lane >= off) { im += vm; ip += vp; }
    }
    __shared__ double wtm[4], wtp[4];
    if (lane == 63) { wtm[wid] = im; wtp[wid] = ip; }
    __syncthreads();
    double bm = im - sm, bp = ip - sp;
    for (int w = 0; w < wid; ++w) { bm += wtm[w]; bp += wtp[w]; }
    #pragma unroll
    for (int j = 0; j < 16; ++j) {
        const size_t tok = base + (size_t)(t * 16 + j) * Gdim;
        cumM[tok] = bm + lm[j];
        cumP[tok] = bp + lp[j];
    }
}

// ---------------------------------------------------------------------------
// Chunked scan over f16 bx (dt already folded in). CHUNKS=128, CLEN=32.
// PASS 0: chunk totals. PASS 1: emit clipped h (f16, in place).
// ---------------------------------------------------------------------------
template<int PASS>
__global__ __launch_bounds__(128) void scan_kernel(
    u16* __restrict__ bxh,
    const double* __restrict__ cumM, const double* __restrict__ cumP,
    const float* __restrict__ logAmag, const float* __restrict__ Aphase,
    float2* __restrict__ Tc, const float2* __restrict__ Pc)
{
    const int c = blockIdx.x;
    const int bg = blockIdx.y;
    const int b = bg >> 2, g = bg & 3;
    const int n = threadIdx.x;
    const double nlAd = (double)(-log1pf(expf(logAmag[g * Ndim + n])));
    const double aphd = (double)(Aphase[g * Ndim + n]);

    float Sr = 0.0f, Si = 0.0f;
    if (PASS == 1) {
        const float2 p = Pc[(size_t)c * NCHAN + bg * Ndim + n];
        Sr = p.x; Si = p.y;
    }
    const int s0 = c * CLEN;
    #pragma unroll 2
    for (int j = 0; j < CLEN; ++j) {
        const int s = s0 + j;
        const size_t tok = ((size_t)(b * Sdim + s)) * Gdim + g;
        const float clr = (float)(nlAd * cumM[tok]);
        const float cli = (float)(aphd * cumP[tok]);
        const float e = expf(clr);                 // underflows to 0 like ref
        float sn, cs;
        sincosf(cli, &sn, &cs);
        const float car = e * cs, cai = e * sn;
        const float dr = car + 1e-12f, di = cai;
        const float inv = 1.0f / (dr * dr + di * di);
        const float bxr = h2f(bxh[tok * 256 + n]);
        const float bxi = h2f(bxh[tok * 256 + 128 + n]);
        Sr += (bxr * dr + bxi * di) * inv;
        Si += (bxi * dr - bxr * di) * inv;
        if (PASS == 1) {
            const float hr  = car * Sr - cai * Si;
            const float hi2 = car * Si + cai * Sr;
            const float nrm = sqrtf(hr * hr + hi2 * hi2 + 1e-8f);
            const float scl = fminf(nrm, 100.0f) / nrm;
            bxh[tok * 256 + n]       = f2h(hr * scl);
            bxh[tok * 256 + 128 + n] = f2h(hi2 * scl);
        }
    }
    if (PASS == 0) Tc[(size_t)c * NCHAN + bg * Ndim + n] = make_float2(Sr, Si);
}

// ---------------------------------------------------------------------------
// Exclusive prefix over chunk totals.
// ---------------------------------------------------------------------------
__global__ __launch_bounds__(256) void chunk_prefix_kernel(
    const float2* __restrict__ Tc, float2* __restrict__ Pc)
{
    const int ch = blockIdx.x * 256 + threadIdx.x;
    if (ch >= NCHAN) return;
    float Sr = 0.0f, Si = 0.0f;
    for (int c = 0; c < CHUNKS; ++c) {
        const float2 t = Tc[(size_t)c * NCHAN + ch];
        Pc[(size_t)c * NCHAN + ch] = make_float2(Sr, Si);
        Sr += t.x; Si += t.y;
    }
}

// ---------------------------------------------------------------------------
// GEMM 2 (MFMA f16, single term): out[M][512] = h[M][256] . Wy[512][256]^T
// ---------------------------------------------------------------------------
__global__ __launch_bounds__(256) void gemm_y_mfma(
    const u16* __restrict__ Hp,
    const u16* __restrict__ Wh,
    float* __restrict__ Cout)
{
    __shared__ u16 sA[128 * 32], sWh[128 * 32];
    const int tid = threadIdx.x, wave = tid >> 6, lane = tid & 63;
    const int i0 = blockIdx.x;                       // 0..2047
    const int wg = (i0 & 7) * 256 + (i0 >> 3);       // bijective XCD chunking
    const size_t m0 = (size_t)(wg >> 2) * 128;
    const int n0 = (wg & 3) * 128;
    const int wm = (wave >> 1) * 64, wn = (wave & 1) * 64;
    f32x4 acc[4][4] = {};
    const int srow = lane >> 2, pslot = lane & 3;

    #pragma unroll 1
    for (int k0 = 0; k0 < 256; k0 += 32) {
        #pragma unroll
        for (int i = 0; i < 2; ++i) {
            const int row = wave * 32 + i * 16 + srow;
            const int lslot = pslot ^ ((row >> 1) & 3);
            const int ldsoff = row * 32 + pslot * 8;
            gl_lds16(Hp + (m0 + row) * 256 + k0 + lslot * 8, sA + ldsoff);
            gl_lds16(Wh + (size_t)(n0 + row) * 256 + k0 + lslot * 8, sWh + ldsoff);
        }
        __syncthreads();

        const int fr = lane & 15, fs = lane >> 4;
        f16x8 a_[4], w_[4];
        #pragma unroll
        for (int f = 0; f < 4; ++f) {
            const int ra = wm + f * 16 + fr;
            a_[f] = *(const f16x8*)&sA [ra * 32 + (fs ^ ((ra >> 1) & 3)) * 8];
            const int rw = wn + f * 16 + fr;
            w_[f] = *(const f16x8*)&sWh[rw * 32 + (fs ^ ((rw >> 1) & 3)) * 8];
        }
        #pragma unroll
        for (int fm = 0; fm < 4; ++fm)
            #pragma unroll
            for (int fn = 0; fn < 4; ++fn)
                acc[fm][fn] = __builtin_amdgcn_mfma_f32_16x16x32_f16(a_[fm], w_[fn], acc[fm][fn], 0, 0, 0);
        __syncthreads();
    }

    const int crow = (lane >> 4) * 4, ccol = lane & 15;
    #pragma unroll
    for (int fm = 0; fm < 4; ++fm)
        #pragma unroll
        for (int fn = 0; fn < 4; ++fn)
            #pragma unroll
            for (int j = 0; j < 4; ++j)
                Cout[(m0 + wm + fm * 16 + crow + j) * 512 + n0 + wn + fn * 16 + ccol] =
                    acc[fm][fn][j];
}

// ---------------------------------------------------------------------------
extern "C" void kernel_launch(void* const* d_in, const int* in_sizes, int n_in,
                              void* d_out, int out_size, void* d_ws, size_t ws_size,
                              hipStream_t stream)
{
    const float* xr      = (const float*)d_in[0];
    const float* xi      = (const float*)d_in[1];
    const float* logAmag = (const float*)d_in[2];
    const float* Aphase  = (const float*)d_in[3];
    const float* Bwr     = (const float*)d_in[4];
    const float* Bwi     = (const float*)d_in[5];
    const float* Cwr     = (const float*)d_in[6];
    const float* Cwi     = (const float*)d_in[7];
    const float* dtw     = (const float*)d_in[8];
    const float* dtb     = (const float*)d_in[9];
    float* out = (float*)d_out;

    char* ws = (char*)d_ws;
    size_t off = 0;
    u16* bxh  = (u16*)(ws + off);  off += (size_t)NTOK * 256 * sizeof(u16);  // 32 MiB
    float* dtm = (float*)(ws + off);  off += (size_t)NTOK * sizeof(float);
    float* dtp = (float*)(ws + off);  off += (size_t)NTOK * sizeof(float);
    double* cumM = (double*)(ws + off); off += (size_t)NTOK * sizeof(double);
    double* cumP = (double*)(ws + off); off += (size_t)NTOK * sizeof(double);
    float2* Tc = (float2*)(ws + off); off += (size_t)CHUNKS * NCHAN * sizeof(float2);
    float2* Pc = (float2*)(ws + off); off += (size_t)CHUNKS * NCHAN * sizeof(float2);
    u16* WbxH = (u16*)(ws + off); off += 256 * 512 * sizeof(u16);
    u16* WyH  = (u16*)(ws + off); off += 512 * 256 * sizeof(u16);

    prep_weights<<<512, 256, 0, stream>>>(Bwr, Bwi, Cwr, Cwi, WbxH, WyH);
    gemm_bx_fused<<<1024, 256, 0, stream>>>(xr, xi, WbxH, dtw, dtb, bxh, dtm, dtp);
    cumsum_kernel<<<Bdim * Gdim, 256, 0, stream>>>(dtm, dtp, cumM, cumP);
    scan_kernel<0><<<dim3(CHUNKS, Bdim * Gdim), 128, 0, stream>>>(
        bxh, cumM, cumP, logAmag, Aphase, Tc, Pc);
    chunk_prefix_kernel<<<(NCHAN + 255) / 256, 256, 0, stream>>>(Tc, Pc);
    scan_kernel<1><<<dim3(CHUNKS, Bdim * Gdim), 128, 0, stream>>>(
        bxh, cumM, cumP, logAmag, Aphase, Tc, Pc);
    gemm_y_mfma<<<2048, 256, 0, stream>>>(bxh, WyH, out);
}

// Round 6
// 133.184 us; speedup vs baseline: 4.2730x; 1.2807x over previous
//
#include <hip/hip_runtime.h>
#include <math.h>

#define Bdim 4
#define Sdim 4096
#define Gdim 4
#define Ddim 256
#define Ndim 128
#define NTOK (Bdim*Sdim*Gdim)      // 65536 tokens
#define CHUNKS 128
#define CLEN (Sdim/CHUNKS)         // 32 steps per chunk == M-tile s-span
#define NCHAN (Bdim*Gdim*Ndim)     // 2048 scan channels
#define NTILE (Bdim*CHUNKS)        // 512 M-tiles of 128 tokens

typedef unsigned short u16;
typedef unsigned int   u32;
typedef unsigned char  u8;
typedef __attribute__((ext_vector_type(8))) _Float16 f16x8;
typedef __attribute__((ext_vector_type(4))) _Float16 f16x4;
typedef __attribute__((ext_vector_type(4))) float f32x4;

#define GLOBAL_AS __attribute__((address_space(1)))
#define LDS_AS    __attribute__((address_space(3)))

__device__ __forceinline__ void gl_lds16(const void* g, void* l) {
    __builtin_amdgcn_global_load_lds((const GLOBAL_AS u32*)g, (LDS_AS u32*)l, 16, 0, 0);
}

union HU { _Float16 h; u16 u; };
__device__ __forceinline__ u16 f2h(float f) { HU c; c.h = (_Float16)f; return c.u; }
__device__ __forceinline__ float h2f(u16 u) { HU c; c.u = u; return (float)c.h; }

// ---------------------------------------------------------------------------
// Weight prep (single f16 term).
// WbxH [256 n][512 k]: n<128: [Bwr | -Bwi]; n>=128: [Bwi | Bwr]
// WyH  [512 d][256 k]: d<256: [Cwr | -Cwi]; d>=256: [Cwi | Cwr]
// ---------------------------------------------------------------------------
__global__ __launch_bounds__(256) void prep_weights(
    const float* __restrict__ Bwr, const float* __restrict__ Bwi,
    const float* __restrict__ Cwr, const float* __restrict__ Cwi,
    u16* __restrict__ WbxH, u16* __restrict__ WyH)
{
    const int idx = blockIdx.x * 256 + threadIdx.x;   // 0..131071
    {
        const int n = idx >> 9, k = idx & 511;
        float v;
        if (n < 128) v = (k < 256) ? Bwr[n * 256 + k] : -Bwi[n * 256 + (k - 256)];
        else         v = (k < 256) ? Bwi[(n - 128) * 256 + k] : Bwr[(n - 128) * 256 + (k - 256)];
        WbxH[idx] = f2h(v);
    }
    {
        const int d = idx >> 8, k = idx & 255;
        float v;
        if (d < 256) v = (k < 128) ? Cwr[d * 128 + k] : -Cwi[d * 128 + (k - 128)];
        else         v = (k < 128) ? Cwi[(d - 256) * 128 + k] : Cwr[(d - 256) * 128 + (k - 128)];
        WyH[idx] = f2h(v);
    }
}

// ---------------------------------------------------------------------------
// dt projection (fp32, full sequence — dt is needed for every token's cumsum).
// One wave per token; coalesced float4 row loads; 6-level shfl reduce.
// ---------------------------------------------------------------------------
__global__ __launch_bounds__(256) void dt_kernel(
    const float* __restrict__ xr, const float* __restrict__ xi,
    const float* __restrict__ dtw, const float* __restrict__ dtb,
    float* __restrict__ dtm, float* __restrict__ dtp)
{
    const int gtid = blockIdx.x * 256 + threadIdx.x;
    const int tok  = gtid >> 6;
    const int lane = gtid & 63;
    if (tok >= NTOK) return;

    const float4 a  = *(const float4*)(xr  + (size_t)tok * Ddim + lane * 4);
    const float4 b4 = *(const float4*)(xi  + (size_t)tok * Ddim + lane * 4);
    const float4 c0 = *(const float4*)(dtw +   0 + lane * 4);
    const float4 d0 = *(const float4*)(dtw + 256 + lane * 4);
    const float4 c1 = *(const float4*)(dtw + 512 + lane * 4);
    const float4 d1 = *(const float4*)(dtw + 768 + lane * 4);

    float r0 = a.x*c0.x + a.y*c0.y + a.z*c0.z + a.w*c0.w
             + b4.x*d0.x + b4.y*d0.y + b4.z*d0.z + b4.w*d0.w;
    float r1 = a.x*c1.x + a.y*c1.y + a.z*c1.z + a.w*c1.w
             + b4.x*d1.x + b4.y*d1.y + b4.z*d1.z + b4.w*d1.w;
    #pragma unroll
    for (int off = 32; off; off >>= 1) {
        r0 += __shfl_down(r0, off);
        r1 += __shfl_down(r1, off);
    }
    if (lane == 0) {
        float m = expf(r0 + dtb[0]); m = fminf(fmaxf(m, 1e-4f), 2.0f);
        float p = expf(r1 + dtb[1]); p = fminf(fmaxf(p, 1e-4f), 2.0f);
        dtm[tok] = m;
        dtp[tok] = p;
    }
}

// ---------------------------------------------------------------------------
// f64 cumsum of dt_mag/dt_phase per (b,g) + per-chunk alive flags.
// Chunk (b,c,g) alive iff the SLOWEST-decaying channel (min softplus) still
// has clr = -minsp*cumM >= -106 at chunk start (expf underflows to exact 0
// below ~-104 in f32 for both us and the f32 reference; 106 is conservative).
// Flag byte layout: aliveF[(b*128+c)*4 + g]; consumers test the u32.
// ---------------------------------------------------------------------------
__global__ __launch_bounds__(256) void cumsum_kernel(
    const float* __restrict__ dtm, const float* __restrict__ dtp,
    const float* __restrict__ logAmag,
    double* __restrict__ cumM, double* __restrict__ cumP,
    u8* __restrict__ aliveF)
{
    const int bg = blockIdx.x, b = bg >> 2, g = bg & 3;
    const int t = threadIdx.x, lane = t & 63, wid = t >> 6;

    // min_n softplus(log_A_mag[g,n])
    __shared__ float sws[4];
    float sp = 1e30f;
    if (t < 128) sp = log1pf(expf(logAmag[g * Ndim + t]));
    #pragma unroll
    for (int off = 32; off; off >>= 1) sp = fminf(sp, __shfl_down(sp, off));
    if (lane == 0) sws[wid] = sp;
    __syncthreads();
    const float minsp = fminf(fminf(sws[0], sws[1]), fminf(sws[2], sws[3]));
    __syncthreads();

    const size_t base = (size_t)b * Sdim * Gdim + g;
    double lm[16], lp[16], sm = 0.0, sp2 = 0.0;
    #pragma unroll
    for (int j = 0; j < 16; ++j) {
        const size_t tok = base + (size_t)(t * 16 + j) * Gdim;
        sm  += (double)dtm[tok]; lm[j] = sm;
        sp2 += (double)dtp[tok]; lp[j] = sp2;
    }
    double im = sm, ip = sp2;
    #pragma unroll
    for (int off = 1; off < 64; off <<= 1) {
        double vm = __shfl_up(im, off);
        double vp = __shfl_up(ip, off);
        if (lane >= off) { im += vm; ip += vp; }
    }
    __shared__ double wtm[4], wtp[4];
    if (lane == 63) { wtm[wid] = im; wtp[wid] = ip; }
    __syncthreads();
    double bm = im - sm, bp = ip - sp2;
    for (int w = 0; w < wid; ++w) { bm += wtm[w]; bp += wtp[w]; }
    #pragma unroll
    for (int j = 0; j < 16; ++j) {
        const size_t tok = base + (size_t)(t * 16 + j) * Gdim;
        cumM[tok] = bm + lm[j];
        cumP[tok] = bp + lp[j];
    }
    if ((t & 1) == 0) {   // t*16 == 32c -> chunk c = t/2 starts at this thread's j=0
        const int c = t >> 1;
        const double cm0 = bm + lm[0];               // inclusive cumM at s=32c
        aliveF[(size_t)(b * CHUNKS + c) * 4 + g] =
            ((double)minsp * cm0 <= 106.0) ? 1 : 0;
    }
}

// ---------------------------------------------------------------------------
// GEMM 1 (MFMA f16): bx[M][256] = (xcat[M][512] . Wbx^T) * dt_mag[M]  (f16)
// Runs ONLY alive M-tiles (dead tiles' bx is never read downstream).
// ---------------------------------------------------------------------------
__global__ __launch_bounds__(256) void gemm_bx_mfma(
    const float* __restrict__ xr, const float* __restrict__ xi,
    const u16* __restrict__ Wh, const float* __restrict__ dtm,
    const u32* __restrict__ aliveT,
    u16* __restrict__ bxh)
{
    const int i0 = blockIdx.x;                       // 0..1023
    const int wg = (i0 & 7) * 128 + (i0 >> 3);       // bijective XCD chunking
    if (aliveT[wg >> 1] == 0) return;

    __shared__ u16 sA[128 * 32], sWh[128 * 32];
    __shared__ float sDtM[128];
    const int tid = threadIdx.x, wave = tid >> 6, lane = tid & 63;
    const size_t m0 = (size_t)(wg >> 1) * 128;
    const int n0 = (wg & 1) * 128;
    const int wm = (wave >> 1) * 64, wn = (wave & 1) * 64;
    f32x4 acc[4][4] = {};
    const int srow = lane >> 2, pslot = lane & 3;

    if (tid < 128) sDtM[tid] = dtm[m0 + tid];

    const int arow = tid >> 3;            // 0..31
    const int acol = (tid & 7) * 4;       // 0..28 within 32-col window
    const int asl  = acol >> 3;
    const int asub = acol & 7;

    #pragma unroll 1
    for (int k0 = 0; k0 < 512; k0 += 32) {
        {   // A: coalesced fp32 load -> f16 ds_write (swizzled)
            const float* xsrc = (k0 < 256) ? xr : xi;
            const int kk = (k0 & 255) + acol;
            #pragma unroll
            for (int i = 0; i < 4; ++i) {
                const int row = arow + 32 * i;
                const float4 v = *(const float4*)(xsrc + (m0 + row) * 256 + kk);
                f16x4 p;
                p[0] = (_Float16)v.x; p[1] = (_Float16)v.y;
                p[2] = (_Float16)v.z; p[3] = (_Float16)v.w;
                *(f16x4*)&sA[row * 32 + (asl ^ ((row >> 1) & 3)) * 8 + asub] = p;
            }
        }
        #pragma unroll
        for (int i = 0; i < 2; ++i) {                // W via global_load_lds
            const int row = wave * 32 + i * 16 + srow;
            const int lslot = pslot ^ ((row >> 1) & 3);
            gl_lds16(Wh + (size_t)(n0 + row) * 512 + k0 + lslot * 8,
                     sWh + row * 32 + pslot * 8);
        }
        __syncthreads();

        const int fr = lane & 15, fs = lane >> 4;
        f16x8 a_[4], w_[4];
        #pragma unroll
        for (int f = 0; f < 4; ++f) {
            const int ra = wm + f * 16 + fr;
            a_[f] = *(const f16x8*)&sA [ra * 32 + (fs ^ ((ra >> 1) & 3)) * 8];
            const int rw = wn + f * 16 + fr;
            w_[f] = *(const f16x8*)&sWh[rw * 32 + (fs ^ ((rw >> 1) & 3)) * 8];
        }
        #pragma unroll
        for (int fm = 0; fm < 4; ++fm)
            #pragma unroll
            for (int fn = 0; fn < 4; ++fn)
                acc[fm][fn] = __builtin_amdgcn_mfma_f32_16x16x32_f16(a_[fm], w_[fn], acc[fm][fn], 0, 0, 0);
        __syncthreads();
    }

    const int crow = (lane >> 4) * 4, ccol = lane & 15;
    #pragma unroll
    for (int fm = 0; fm < 4; ++fm)
        #pragma unroll
        for (int fn = 0; fn < 4; ++fn)
            #pragma unroll
            for (int j = 0; j < 4; ++j) {
                const int rl = wm + fm * 16 + crow + j;
                bxh[(m0 + rl) * 256 + n0 + wn + fn * 16 + ccol] =
                    f2h(acc[fm][fn][j] * sDtM[rl]);
            }
}

// ---------------------------------------------------------------------------
// Chunked scan over f16 bx (dt folded in). CHUNKS=128, CLEN=32.
// PASS 0: per-channel early-out when exp(clr)=0 at chunk start (monotone ->
//         dead forever; downstream h = 0*S regardless of prefix) -> Tc=0.
// PASS 1: skip whole tile when flag says every (g,n) is dead (gemm_y writes
//         zeros there and never reads h); alive tiles compute naturally
//         (dead channels produce exact 0 via car=cai=0).
// ---------------------------------------------------------------------------
template<int PASS>
__global__ __launch_bounds__(128) void scan_kernel(
    u16* __restrict__ bxh,
    const double* __restrict__ cumM, const double* __restrict__ cumP,
    const float* __restrict__ logAmag, const float* __restrict__ Aphase,
    const u32* __restrict__ aliveT,
    float2* __restrict__ Tc, const float2* __restrict__ Pc)
{
    const int c = blockIdx.x;
    const int bg = blockIdx.y;
    const int b = bg >> 2, g = bg & 3;
    const int n = threadIdx.x;
    if (PASS == 1 && aliveT[b * CHUNKS + c] == 0) return;

    const double nlAd = (double)(-log1pf(expf(logAmag[g * Ndim + n])));
    const double aphd = (double)(Aphase[g * Ndim + n]);
    const int s0 = c * CLEN;

    if (PASS == 0) {
        const size_t tok0 = ((size_t)(b * Sdim + s0)) * Gdim + g;
        const float clr0 = (float)(nlAd * cumM[tok0]);
        if (expf(clr0) == 0.0f) {
            Tc[(size_t)c * NCHAN + bg * Ndim + n] = make_float2(0.0f, 0.0f);
            return;
        }
    }

    float Sr = 0.0f, Si = 0.0f;
    if (PASS == 1) {
        const float2 p = Pc[(size_t)c * NCHAN + bg * Ndim + n];
        Sr = p.x; Si = p.y;
    }
    #pragma unroll 2
    for (int j = 0; j < CLEN; ++j) {
        const int s = s0 + j;
        const size_t tok = ((size_t)(b * Sdim + s)) * Gdim + g;
        const float clr = (float)(nlAd * cumM[tok]);
        const float cli = (float)(aphd * cumP[tok]);
        const float e = expf(clr);                 // underflows to 0 like ref
        float sn, cs;
        sincosf(cli, &sn, &cs);
        const float car = e * cs, cai = e * sn;
        const float dr = car + 1e-12f, di = cai;
        const float inv = 1.0f / (dr * dr + di * di);
        const float bxr = h2f(bxh[tok * 256 + n]);
        const float bxi = h2f(bxh[tok * 256 + 128 + n]);
        Sr += (bxr * dr + bxi * di) * inv;
        Si += (bxi * dr - bxr * di) * inv;
        if (PASS == 1) {
            const float hr  = car * Sr - cai * Si;
            const float hi2 = car * Si + cai * Sr;
            const float nrm = sqrtf(hr * hr + hi2 * hi2 + 1e-8f);
            const float scl = fminf(nrm, 100.0f) / nrm;
            bxh[tok * 256 + n]       = f2h(hr * scl);
            bxh[tok * 256 + 128 + n] = f2h(hi2 * scl);
        }
    }
    if (PASS == 0) Tc[(size_t)c * NCHAN + bg * Ndim + n] = make_float2(Sr, Si);
}

// ---------------------------------------------------------------------------
// Exclusive prefix over chunk totals.
// ---------------------------------------------------------------------------
__global__ __launch_bounds__(256) void chunk_prefix_kernel(
    const float2* __restrict__ Tc, float2* __restrict__ Pc)
{
    const int ch = blockIdx.x * 256 + threadIdx.x;
    if (ch >= NCHAN) return;
    float Sr = 0.0f, Si = 0.0f;
    for (int c = 0; c < CHUNKS; ++c) {
        const float2 t = Tc[(size_t)c * NCHAN + ch];
        Pc[(size_t)c * NCHAN + ch] = make_float2(Sr, Si);
        Sr += t.x; Si += t.y;
    }
}

// ---------------------------------------------------------------------------
// GEMM 2 (MFMA f16): out[M][512] = h[M][256] . Wy[512][256]^T
// Dead tiles: write zeros (ref y there is <=1e-20), no loads, no MFMA.
// ---------------------------------------------------------------------------
__global__ __launch_bounds__(256) void gemm_y_mfma(
    const u16* __restrict__ Hp,
    const u16* __restrict__ Wh,
    const u32* __restrict__ aliveT,
    float* __restrict__ Cout)
{
    const int tid = threadIdx.x;
    const int i0 = blockIdx.x;                       // 0..2047
    const int wg = (i0 & 7) * 256 + (i0 >> 3);       // bijective XCD chunking
    const size_t m0 = (size_t)(wg >> 2) * 128;
    const int n0 = (wg & 3) * 128;

    if (aliveT[wg >> 2] == 0) {                      // dead tile -> zero-fill
        const float4 z = make_float4(0.f, 0.f, 0.f, 0.f);
        #pragma unroll
        for (int it = 0; it < 16; ++it) {
            const int row = it * 8 + (tid >> 5);
            *(float4*)&Cout[(m0 + row) * 512 + n0 + (tid & 31) * 4] = z;
        }
        return;
    }

    __shared__ u16 sA[128 * 32], sWh[128 * 32];
    const int wave = tid >> 6, lane = tid & 63;
    const int wm = (wave >> 1) * 64, wn = (wave & 1) * 64;
    f32x4 acc[4][4] = {};
    const int srow = lane >> 2, pslot = lane & 3;

    #pragma unroll 1
    for (int k0 = 0; k0 < 256; k0 += 32) {
        #pragma unroll
        for (int i = 0; i < 2; ++i) {
            const int row = wave * 32 + i * 16 + srow;
            const int lslot = pslot ^ ((row >> 1) & 3);
            const int ldsoff = row * 32 + pslot * 8;
            gl_lds16(Hp + (m0 + row) * 256 + k0 + lslot * 8, sA + ldsoff);
            gl_lds16(Wh + (size_t)(n0 + row) * 256 + k0 + lslot * 8, sWh + ldsoff);
        }
        __syncthreads();

        const int fr = lane & 15, fs = lane >> 4;
        f16x8 a_[4], w_[4];
        #pragma unroll
        for (int f = 0; f < 4; ++f) {
            const int ra = wm + f * 16 + fr;
            a_[f] = *(const f16x8*)&sA [ra * 32 + (fs ^ ((ra >> 1) & 3)) * 8];
            const int rw = wn + f * 16 + fr;
            w_[f] = *(const f16x8*)&sWh[rw * 32 + (fs ^ ((rw >> 1) & 3)) * 8];
        }
        #pragma unroll
        for (int fm = 0; fm < 4; ++fm)
            #pragma unroll
            for (int fn = 0; fn < 4; ++fn)
                acc[fm][fn] = __builtin_amdgcn_mfma_f32_16x16x32_f16(a_[fm], w_[fn], acc[fm][fn], 0, 0, 0);
        __syncthreads();
    }

    const int crow = (lane >> 4) * 4, ccol = lane & 15;
    #pragma unroll
    for (int fm = 0; fm < 4; ++fm)
        #pragma unroll
        for (int fn = 0; fn < 4; ++fn)
            #pragma unroll
            for (int j = 0; j < 4; ++j)
                Cout[(m0 + wm + fm * 16 + crow + j) * 512 + n0 + wn + fn * 16 + ccol] =
                    acc[fm][fn][j];
}

// ---------------------------------------------------------------------------
extern "C" void kernel_launch(void* const* d_in, const int* in_sizes, int n_in,
                              void* d_out, int out_size, void* d_ws, size_t ws_size,
                              hipStream_t stream)
{
    const float* xr      = (const float*)d_in[0];
    const float* xi      = (const float*)d_in[1];
    const float* logAmag = (const float*)d_in[2];
    const float* Aphase  = (const float*)d_in[3];
    const float* Bwr     = (const float*)d_in[4];
    const float* Bwi     = (const float*)d_in[5];
    const float* Cwr     = (const float*)d_in[6];
    const float* Cwi     = (const float*)d_in[7];
    const float* dtw     = (const float*)d_in[8];
    const float* dtb     = (const float*)d_in[9];
    float* out = (float*)d_out;

    char* ws = (char*)d_ws;
    size_t off = 0;
    u16* bxh  = (u16*)(ws + off);  off += (size_t)NTOK * 256 * sizeof(u16);  // 32 MiB
    float* dtm = (float*)(ws + off);  off += (size_t)NTOK * sizeof(float);
    float* dtp = (float*)(ws + off);  off += (size_t)NTOK * sizeof(float);
    double* cumM = (double*)(ws + off); off += (size_t)NTOK * sizeof(double);
    double* cumP = (double*)(ws + off); off += (size_t)NTOK * sizeof(double);
    float2* Tc = (float2*)(ws + off); off += (size_t)CHUNKS * NCHAN * sizeof(float2);
    float2* Pc = (float2*)(ws + off); off += (size_t)CHUNKS * NCHAN * sizeof(float2);
    u16* WbxH = (u16*)(ws + off); off += 256 * 512 * sizeof(u16);
    u16* WyH  = (u16*)(ws + off); off += 512 * 256 * sizeof(u16);
    u8* aliveF = (u8*)(ws + off); off += NTILE * 4;

    prep_weights<<<512, 256, 0, stream>>>(Bwr, Bwi, Cwr, Cwi, WbxH, WyH);
    dt_kernel<<<NTOK / 4, 256, 0, stream>>>(xr, xi, dtw, dtb, dtm, dtp);
    cumsum_kernel<<<Bdim * Gdim, 256, 0, stream>>>(dtm, dtp, logAmag, cumM, cumP, aliveF);
    gemm_bx_mfma<<<1024, 256, 0, stream>>>(xr, xi, WbxH, dtm, (const u32*)aliveF, bxh);
    scan_kernel<0><<<dim3(CHUNKS, Bdim * Gdim), 128, 0, stream>>>(
        bxh, cumM, cumP, logAmag, Aphase, (const u32*)aliveF, Tc, Pc);
    chunk_prefix_kernel<<<(NCHAN + 255) / 256, 256, 0, stream>>>(Tc, Pc);
    scan_kernel<1><<<dim3(CHUNKS, Bdim * Gdim), 128, 0, stream>>>(
        bxh, cumM, cumP, logAmag, Aphase, (const u32*)aliveF, Tc, Pc);
    gemm_y_mfma<<<2048, 256, 0, stream>>>(bxh, WyH, (const u32*)aliveF, out);
}